// Round 6
// baseline (5211.643 us; speedup 1.0000x reference)
//
#include <hip/hip_runtime.h>
#include <hip/hip_bf16.h>

// Problem constants
#define B_   64
#define N_   200
#define S_   201
#define E_   128
#define H_   8
#define D_   16
#define HD_  128
#define FF_  512
#define L_   6
#define TWOH_ 16
#define NCH_ 2              // n's per attn block
#define NCHB_ 101           // ceil(S_/NCH_)
#define PADM_ 208           // padded m stride for PL

// ---------------- initial embedding ----------------
__global__ void embed_kernel(const float* __restrict__ depot, const float* __restrict__ node,
                             const float* __restrict__ Wd, const float* __restrict__ bd,
                             const float* __restrict__ Wn, const float* __restrict__ bn,
                             float* __restrict__ X) {
  int idx = blockIdx.x * blockDim.x + threadIdx.x;
  if (idx >= B_ * S_ * E_) return;
  int e  = idx & (E_ - 1);
  int bs = idx >> 7;
  int s  = bs % S_;
  int b  = bs / S_;
  float acc;
  if (s == 0) {
    acc = bd[e];
    #pragma unroll
    for (int i = 0; i < 3; ++i) acc += depot[b * 3 + i] * Wd[i * E_ + e];
  } else {
    acc = bn[e];
    const float* nd = node + ((size_t)b * N_ + (s - 1)) * 4;
    #pragma unroll
    for (int i = 0; i < 4; ++i) acc += nd[i] * Wn[i * E_ + e];
  }
  X[idx] = acc;
}

// ---------------- generic tiled GEMM (f32) ----------------
__global__ __launch_bounds__(256) void gemm_kernel(
    const float* __restrict__ A, const float* __restrict__ W,
    const float* __restrict__ bias, const float* __restrict__ res,
    float* __restrict__ C, int M, int N, int K, int relu) {
  __shared__ float As[64][33];
  __shared__ float Ws[32][64];
  int tid = threadIdx.x;
  int m0 = blockIdx.x * 64;
  int n0 = blockIdx.y * 64;
  int tx = tid & 15, ty = tid >> 4;
  float acc[4][4] = {};
  for (int k0 = 0; k0 < K; k0 += 32) {
    {
      int p = tid * 8;
      int r = p >> 5, c = p & 31;
      const float* src = A + (size_t)(m0 + r) * K + k0 + c;
      #pragma unroll
      for (int i = 0; i < 8; ++i) As[r][c + i] = src[i];
    }
    {
      int p = tid * 8;
      int r = p >> 6, c = p & 63;
      const float* src = W + (size_t)(k0 + r) * N + n0 + c;
      #pragma unroll
      for (int i = 0; i < 8; ++i) Ws[r][c + i] = src[i];
    }
    __syncthreads();
    #pragma unroll
    for (int kk = 0; kk < 32; ++kk) {
      float a[4], w[4];
      #pragma unroll
      for (int i = 0; i < 4; ++i) a[i] = As[ty * 4 + i][kk];
      #pragma unroll
      for (int j = 0; j < 4; ++j) w[j] = Ws[kk][tx * 4 + j];
      #pragma unroll
      for (int i = 0; i < 4; ++i)
        #pragma unroll
        for (int j = 0; j < 4; ++j) acc[i][j] += a[i] * w[j];
    }
    __syncthreads();
  }
  #pragma unroll
  for (int i = 0; i < 4; ++i) {
    int m = m0 + ty * 4 + i;
    #pragma unroll
    for (int j = 0; j < 4; ++j) {
      int n = n0 + tx * 4 + j;
      float v = acc[i][j];
      if (bias) v += bias[n];
      if (res)  v += res[(size_t)m * N + n];
      if (relu) v = v > 0.f ? v : 0.f;
      C[(size_t)m * N + n] = v;
    }
  }
}

// ---------------- attention scores ----------------
__global__ __launch_bounds__(256) void score_kernel(const float* __restrict__ Q,
                                                    const float* __restrict__ Kmat,
                                                    float* __restrict__ SC) {
  int bh = blockIdx.x;
  int h = bh % H_, b = bh / H_;
  __shared__ float qs[S_][D_ + 1];
  __shared__ float ks[S_][D_ + 1];
  int tid = threadIdx.x;
  for (int p = tid; p < S_ * D_; p += 256) {
    int r = p >> 4, d = p & 15;
    size_t g = ((size_t)(b * S_ + r)) * HD_ + h * D_ + d;
    qs[r][d] = Q[g];
    ks[r][d] = Kmat[g];
  }
  __syncthreads();
  float* out = SC + ((size_t)(b * H_ + h)) * S_ * S_;
  for (int p = tid; p < S_ * S_; p += 256) {
    int n = p / S_, m = p - n * S_;
    float acc = 0.f;
    #pragma unroll
    for (int d = 0; d < D_; ++d) acc += qs[n][d] * ks[m][d];
    out[(size_t)n * S_ + m] = acc;
  }
}

// ---------------- fused: edge-MLP + softmax + PV, 2 n's per block ----------------
__global__ __launch_bounds__(256) void attn_kernel(
    const float* __restrict__ SC, const float* __restrict__ RA,
    const float* __restrict__ A1w, const float* __restrict__ A1b,
    const float* __restrict__ A2w, const float* __restrict__ A2b,
    const float* __restrict__ V, float* __restrict__ O) {
  int blk = blockIdx.x;
  int b  = blk / NCHB_;
  int n0 = (blk % NCHB_) * NCH_;
  int NV = min(NCH_, S_ - n0);
  __shared__ float PL[NCH_][H_][PADM_];
  __shared__ float partial[2][NCH_][H_][D_];
  __shared__ float inv[NCH_][H_];
  __shared__ float4 w1s[TWOH_][4];   // w1s[i][q] = A1w[i][4q..4q+3]
  __shared__ float4 w2s[TWOH_][2];   // w2s[j][q] = A2w[j][4q..4q+3]
  __shared__ float b1s[TWOH_];
  __shared__ float b2s[H_];
  int tid = threadIdx.x;

  // stage MLP weights in LDS (vectorized)
  if (tid < 64)                ((float4*)w1s)[tid]      = ((const float4*)A1w)[tid];
  else if (tid < 96)           ((float4*)w2s)[tid - 64] = ((const float4*)A2w)[tid - 64];
  if (tid < TWOH_)             b1s[tid] = A1b[tid];
  if (tid < H_)                b2s[tid] = A2b[tid];

  // ---- phase 1: edge MLP, 2 edges per thread, inputs straight from global ----
  float cc[2][16];
  int   mm[2], nnv[2];
  bool  val[2];
  #pragma unroll
  for (int k = 0; k < 2; ++k) {
    int e = tid + 256 * k;
    val[k] = (e < NV * S_);
    int nn = (e >= S_) ? 1 : 0;
    int m  = e - nn * S_;
    nnv[k] = nn; mm[k] = m;
    #pragma unroll
    for (int h = 0; h < H_; ++h) {
      size_t r = (((size_t)b * H_ + h) * S_ + (n0 + nn)) * S_ + m;
      cc[k][h]      = val[k] ? SC[r] : 0.f;
      cc[k][H_ + h] = val[k] ? RA[r] : 0.f;
    }
  }
  __syncthreads();   // weights staged
  {
    float h1[2][16];
    #pragma unroll
    for (int j = 0; j < 16; ++j) { float bj = b1s[j]; h1[0][j] = bj; h1[1][j] = bj; }
    #pragma unroll
    for (int i = 0; i < 16; ++i) {
      float c0 = cc[0][i], c1 = cc[1][i];
      #pragma unroll
      for (int q = 0; q < 4; ++q) {
        float4 w = w1s[i][q];   // broadcast ds_read_b128
        h1[0][4*q+0] += c0 * w.x;  h1[1][4*q+0] += c1 * w.x;
        h1[0][4*q+1] += c0 * w.y;  h1[1][4*q+1] += c1 * w.y;
        h1[0][4*q+2] += c0 * w.z;  h1[1][4*q+2] += c1 * w.z;
        h1[0][4*q+3] += c0 * w.w;  h1[1][4*q+3] += c1 * w.w;
      }
    }
    float agg[2][8];
    #pragma unroll
    for (int h = 0; h < 8; ++h) { float bh = b2s[h]; agg[0][h] = bh; agg[1][h] = bh; }
    #pragma unroll
    for (int j = 0; j < 16; ++j) {
      float r0 = fmaxf(h1[0][j], 0.f), r1 = fmaxf(h1[1][j], 0.f);
      #pragma unroll
      for (int q = 0; q < 2; ++q) {
        float4 w = w2s[j][q];
        agg[0][4*q+0] += r0 * w.x;  agg[1][4*q+0] += r1 * w.x;
        agg[0][4*q+1] += r0 * w.y;  agg[1][4*q+1] += r1 * w.y;
        agg[0][4*q+2] += r0 * w.z;  agg[1][4*q+2] += r1 * w.z;
        agg[0][4*q+3] += r0 * w.w;  agg[1][4*q+3] += r1 * w.w;
      }
    }
    #pragma unroll
    for (int k = 0; k < 2; ++k)
      if (val[k]) {
        #pragma unroll
        for (int h = 0; h < 8; ++h) PL[nnv[k]][h][mm[k]] = agg[k][h];
      }
  }
  __syncthreads();

  // ---- phase 2: softmax over m, 16 lanes per (nn,h) group ----
  {
    int g = tid >> 4, lane = tid & 15;
    int nn = g >> 3, h = g & 7;
    if (nn < NV) {
      float mx = -1e30f;
      for (int m = lane; m < S_; m += 16) mx = fmaxf(mx, PL[nn][h][m]);
      #pragma unroll
      for (int off = 1; off < 16; off <<= 1) mx = fmaxf(mx, __shfl_xor(mx, off));
      float sum = 0.f;
      for (int m = lane; m < S_; m += 16) {
        float e = __expf(PL[nn][h][m] - mx);
        PL[nn][h][m] = e;
        sum += e;
      }
      #pragma unroll
      for (int off = 1; off < 16; off <<= 1) sum += __shfl_xor(sum, off);
      if (lane == 0) inv[nn][h] = 1.f / sum;
    }
  }
  __syncthreads();

  // ---- phase 3: PV, all 256 threads: (half of m) x (h,d); 2 n-accumulators per load ----
  {
    int half = tid >> 7, h = (tid >> 4) & 7, d = tid & 15;
    float a0 = 0.f, a1 = 0.f;
    const float* vp = V + (size_t)b * S_ * HD_ + h * D_ + d;
    for (int m = half; m < S_; m += 2) {
      float vv = vp[(size_t)m * HD_];
      a0 += PL[0][h][m] * vv;
      a1 += PL[1][h][m] * vv;
    }
    partial[half][0][h][d] = a0;
    partial[half][1][h][d] = a1;
  }
  __syncthreads();
  if (tid < 128) {
    int h = tid >> 4, d = tid & 15;
    #pragma unroll
    for (int nn = 0; nn < NCH_; ++nn)
      if (nn < NV) {
        float s = (partial[0][nn][h][d] + partial[1][nn][h][d]) * inv[nn][h];
        O[((size_t)b * S_ + (n0 + nn)) * HD_ + h * D_ + d] = s;
      }
  }
}

// ---------------- instance norm over sequence axis ----------------
__global__ __launch_bounds__(512) void inorm_kernel(const float* __restrict__ Y,
                                                    const float* __restrict__ w,
                                                    const float* __restrict__ bb,
                                                    float* __restrict__ X) {
  int b = blockIdx.x;
  int tid = threadIdx.x;
  int e = tid & 127, sg = tid >> 7;
  __shared__ float ps[4][128], pss[4][128];
  const float* base = Y + (size_t)b * S_ * E_;
  float s = 0.f, ss = 0.f;
  for (int i = sg; i < S_; i += 4) {
    float v = base[(size_t)i * E_ + e];
    s += v; ss += v * v;
  }
  ps[sg][e] = s; pss[sg][e] = ss;
  __syncthreads();
  if (sg == 0) {
    s  = ps[0][e] + ps[1][e] + ps[2][e] + ps[3][e];
    ss = pss[0][e] + pss[1][e] + pss[2][e] + pss[3][e];
    float mean = s / S_;
    float var  = fmaxf(ss / S_ - mean * mean, 0.f);
    float scale = rsqrtf(var + 1e-5f) * w[e];
    ps[0][e]  = scale;
    pss[0][e] = bb[e] - mean * scale;
  }
  __syncthreads();
  float scale = ps[0][e], shift = pss[0][e];
  float* dst = X + (size_t)b * S_ * E_;
  for (int i = sg; i < S_; i += 4) {
    size_t idx = (size_t)i * E_ + e;
    dst[idx] = base[idx] * scale + shift;
  }
}

extern "C" void kernel_launch(void* const* d_in, const int* in_sizes, int n_in,
                              void* d_out, int out_size, void* d_ws, size_t ws_size,
                              hipStream_t stream) {
  const float* depot = (const float*)d_in[0];
  const float* node  = (const float*)d_in[1];
  const float* RA    = (const float*)d_in[2];
  const float* Wd    = (const float*)d_in[3];
  const float* bd    = (const float*)d_in[4];
  const float* Wn    = (const float*)d_in[5];
  const float* bn    = (const float*)d_in[6];
  const float* Wq    = (const float*)d_in[7];
  const float* Wk    = (const float*)d_in[8];
  const float* Wv    = (const float*)d_in[9];
  const float* Wo    = (const float*)d_in[10];
  const float* bo    = (const float*)d_in[11];
  const float* A1w   = (const float*)d_in[12];
  const float* A1b   = (const float*)d_in[13];
  const float* A2w   = (const float*)d_in[14];
  const float* A2b   = (const float*)d_in[15];
  const float* n1w   = (const float*)d_in[16];
  const float* n1b   = (const float*)d_in[17];
  const float* n2w   = (const float*)d_in[18];
  const float* n2b   = (const float*)d_in[19];
  const float* F1w   = (const float*)d_in[20];
  const float* F1b   = (const float*)d_in[21];
  const float* F2w   = (const float*)d_in[22];
  const float* F2b   = (const float*)d_in[23];

  const size_t XSZ  = (size_t)B_ * S_ * E_;
  const size_t SCSZ = (size_t)B_ * H_ * S_ * S_;
  float* ws = (float*)d_ws;
  float* X   = ws;
  float* Q   = X  + XSZ;
  float* Kb  = Q  + XSZ;
  float* V   = Kb + XSZ;
  float* O   = V  + XSZ;
  float* SC  = O  + XSZ;
  float* TMP = SC;            // aliases SC (SC consumed before TMP written)
  float* HID = SC + XSZ;      // aliases SC tail

  const int M = B_ * S_;

  auto gemm = [&](const float* A, const float* W, const float* bias,
                  const float* res, float* C, int Nn, int K, int relu) {
    dim3 grid(M / 64, Nn / 64);
    gemm_kernel<<<grid, 256, 0, stream>>>(A, W, bias, res, C, M, Nn, K, relu);
  };

  embed_kernel<<<(B_ * S_ * E_ + 255) / 256, 256, 0, stream>>>(depot, node, Wd, bd, Wn, bn, X);

  for (int l = 0; l < L_; ++l) {
    gemm(X, Wq + (size_t)l * E_ * HD_, nullptr, nullptr, Q,  HD_, E_, 0);
    gemm(X, Wk + (size_t)l * E_ * HD_, nullptr, nullptr, Kb, HD_, E_, 0);
    gemm(X, Wv + (size_t)l * E_ * HD_, nullptr, nullptr, V,  HD_, E_, 0);
    score_kernel<<<B_ * H_, 256, 0, stream>>>(Q, Kb, SC);
    attn_kernel<<<B_ * NCHB_, 256, 0, stream>>>(SC, RA,
        A1w + (size_t)l * TWOH_ * TWOH_, A1b + (size_t)l * TWOH_,
        A2w + (size_t)l * TWOH_ * H_,    A2b + (size_t)l * H_, V, O);
    gemm(O, Wo + (size_t)l * HD_ * E_, bo + (size_t)l * E_, X, TMP, E_, HD_, 0);
    inorm_kernel<<<B_, 512, 0, stream>>>(TMP, n1w + (size_t)l * E_, n1b + (size_t)l * E_, X);
    gemm(X, F1w + (size_t)l * E_ * FF_, F1b + (size_t)l * FF_, nullptr, HID, FF_, E_, 1);
    gemm(HID, F2w + (size_t)l * FF_ * E_, F2b + (size_t)l * E_, X, TMP, E_, FF_, 0);
    float* dst = (l == L_ - 1) ? (float*)d_out : X;
    inorm_kernel<<<B_, 512, 0, stream>>>(TMP, n2w + (size_t)l * E_, n2b + (size_t)l * E_, dst);
  }
}

// Round 7
// 2732.252 us; speedup vs baseline: 1.9075x; 1.9075x over previous
//
#include <hip/hip_runtime.h>
#include <hip/hip_bf16.h>

// Problem constants
#define B_   64
#define N_   200
#define S_   201
#define E_   128
#define H_   8
#define D_   16
#define HD_  128
#define FF_  512
#define L_   6
#define TWOH_ 16
#define PADM_ 208           // padded m stride for PL

// ---------------- initial embedding ----------------
__global__ void embed_kernel(const float* __restrict__ depot, const float* __restrict__ node,
                             const float* __restrict__ Wd, const float* __restrict__ bd,
                             const float* __restrict__ Wn, const float* __restrict__ bn,
                             float* __restrict__ X) {
  int idx = blockIdx.x * blockDim.x + threadIdx.x;
  if (idx >= B_ * S_ * E_) return;
  int e  = idx & (E_ - 1);
  int bs = idx >> 7;
  int s  = bs % S_;
  int b  = bs / S_;
  float acc;
  if (s == 0) {
    acc = bd[e];
    #pragma unroll
    for (int i = 0; i < 3; ++i) acc += depot[b * 3 + i] * Wd[i * E_ + e];
  } else {
    acc = bn[e];
    const float* nd = node + ((size_t)b * N_ + (s - 1)) * 4;
    #pragma unroll
    for (int i = 0; i < 4; ++i) acc += nd[i] * Wn[i * E_ + e];
  }
  X[idx] = acc;
}

// ---------------- generic tiled GEMM (f32) ----------------
__global__ __launch_bounds__(256) void gemm_kernel(
    const float* __restrict__ A, const float* __restrict__ W,
    const float* __restrict__ bias, const float* __restrict__ res,
    float* __restrict__ C, int M, int N, int K, int relu) {
  __shared__ float As[64][33];
  __shared__ float Ws[32][64];
  int tid = threadIdx.x;
  int m0 = blockIdx.x * 64;
  int n0 = blockIdx.y * 64;
  int tx = tid & 15, ty = tid >> 4;
  float acc[4][4] = {};
  for (int k0 = 0; k0 < K; k0 += 32) {
    {
      int p = tid * 8;
      int r = p >> 5, c = p & 31;
      const float* src = A + (size_t)(m0 + r) * K + k0 + c;
      #pragma unroll
      for (int i = 0; i < 8; ++i) As[r][c + i] = src[i];
    }
    {
      int p = tid * 8;
      int r = p >> 6, c = p & 63;
      const float* src = W + (size_t)(k0 + r) * N + n0 + c;
      #pragma unroll
      for (int i = 0; i < 8; ++i) Ws[r][c + i] = src[i];
    }
    __syncthreads();
    #pragma unroll
    for (int kk = 0; kk < 32; ++kk) {
      float a[4], w[4];
      #pragma unroll
      for (int i = 0; i < 4; ++i) a[i] = As[ty * 4 + i][kk];
      #pragma unroll
      for (int j = 0; j < 4; ++j) w[j] = Ws[kk][tx * 4 + j];
      #pragma unroll
      for (int i = 0; i < 4; ++i)
        #pragma unroll
        for (int j = 0; j < 4; ++j) acc[i][j] += a[i] * w[j];
    }
    __syncthreads();
  }
  #pragma unroll
  for (int i = 0; i < 4; ++i) {
    int m = m0 + ty * 4 + i;
    #pragma unroll
    for (int j = 0; j < 4; ++j) {
      int n = n0 + tx * 4 + j;
      float v = acc[i][j];
      if (bias) v += bias[n];
      if (res)  v += res[(size_t)m * N + n];
      if (relu) v = v > 0.f ? v : 0.f;
      C[(size_t)m * N + n] = v;
    }
  }
}

// ---------------- attention scores ----------------
__global__ __launch_bounds__(256) void score_kernel(const float* __restrict__ Q,
                                                    const float* __restrict__ Kmat,
                                                    float* __restrict__ SC) {
  int bh = blockIdx.x;
  int h = bh % H_, b = bh / H_;
  __shared__ float qs[S_][D_ + 1];
  __shared__ float ks[S_][D_ + 1];
  int tid = threadIdx.x;
  for (int p = tid; p < S_ * D_; p += 256) {
    int r = p >> 4, d = p & 15;
    size_t g = ((size_t)(b * S_ + r)) * HD_ + h * D_ + d;
    qs[r][d] = Q[g];
    ks[r][d] = Kmat[g];
  }
  __syncthreads();
  float* out = SC + ((size_t)(b * H_ + h)) * S_ * S_;
  for (int p = tid; p < S_ * S_; p += 256) {
    int n = p / S_, m = p - n * S_;
    float acc = 0.f;
    #pragma unroll
    for (int d = 0; d < D_; ++d) acc += qs[n][d] * ks[m][d];
    out[(size_t)n * S_ + m] = acc;
  }
}

// ---------------- fused: edge-MLP + softmax + PV, one n per block ----------------
// Weights read via uniform (scalar) loads -> SGPR operands; no LDS for weights.
__global__ __launch_bounds__(256) void attn_kernel(
    const float* __restrict__ SC, const float* __restrict__ RA,
    const float* __restrict__ A1w, const float* __restrict__ A1b,
    const float* __restrict__ A2w, const float* __restrict__ A2b,
    const float* __restrict__ V, float* __restrict__ O) {
  int bn = blockIdx.x;
  int n = bn % S_, b = bn / S_;
  __shared__ float cat[S_][TWOH_ + 1];
  __shared__ float PL[H_][PADM_];
  __shared__ float partial[2][H_][D_];
  __shared__ float inv[H_];
  int tid = threadIdx.x;

  // ---- load cat: coalesced along m per head ----
  for (int p = tid; p < H_ * S_; p += 256) {
    int h = p / S_, m = p - h * S_;
    size_t g = (((size_t)b * H_ + h) * S_ + n) * S_ + m;
    cat[m][h]      = SC[g];
    cat[m][H_ + h] = RA[g];
  }
  __syncthreads();

  // ---- edge MLP, one thread per m; weights via scalar loads ----
  if (tid < S_) {
    int m = tid;
    float cc[TWOH_];
    #pragma unroll
    for (int i = 0; i < TWOH_; ++i) cc[i] = cat[m][i];
    float h1[TWOH_];
    #pragma unroll
    for (int j = 0; j < TWOH_; ++j) h1[j] = A1b[j];       // uniform -> s_load
    #pragma unroll
    for (int i = 0; i < TWOH_; ++i) {
      float c = cc[i];
      #pragma unroll
      for (int j = 0; j < TWOH_; ++j)
        h1[j] += c * A1w[i * TWOH_ + j];                  // uniform -> SGPR operand
    }
    float agg[H_];
    #pragma unroll
    for (int h = 0; h < H_; ++h) agg[h] = A2b[h];
    #pragma unroll
    for (int j = 0; j < TWOH_; ++j) {
      float r = fmaxf(h1[j], 0.f);
      #pragma unroll
      for (int h = 0; h < H_; ++h)
        agg[h] += r * A2w[j * H_ + h];
    }
    #pragma unroll
    for (int h = 0; h < H_; ++h) PL[h][m] = agg[h];
  }
  __syncthreads();

  // ---- softmax over m for each head: 8 groups of 32 lanes ----
  {
    int g = tid >> 5;      // head
    int lane = tid & 31;
    float mx = -1e30f;
    for (int m = lane; m < S_; m += 32) mx = fmaxf(mx, PL[g][m]);
    #pragma unroll
    for (int off = 16; off > 0; off >>= 1) mx = fmaxf(mx, __shfl_xor(mx, off, 32));
    float sum = 0.f;
    for (int m = lane; m < S_; m += 32) {
      float e = __expf(PL[g][m] - mx);
      PL[g][m] = e;
      sum += e;
    }
    #pragma unroll
    for (int off = 16; off > 0; off >>= 1) sum += __shfl_xor(sum, off, 32);
    if (lane == 0) inv[g] = 1.f / sum;
  }
  __syncthreads();

  // ---- PV: all 256 threads: (m-parity) x (h,d) ----
  {
    int half = tid >> 7, h = (tid >> 4) & 7, d = tid & 15;
    float a0 = 0.f;
    const float* vp = V + (size_t)b * S_ * HD_ + h * D_ + d;
    for (int m = half; m < S_; m += 2)
      a0 += PL[h][m] * vp[(size_t)m * HD_];
    partial[half][h][d] = a0;
  }
  __syncthreads();
  if (tid < 128) {
    int h = tid >> 4, d = tid & 15;
    float s = (partial[0][h][d] + partial[1][h][d]) * inv[h];
    O[((size_t)b * S_ + n) * HD_ + h * D_ + d] = s;
  }
}

// ---------------- instance norm over sequence axis ----------------
__global__ __launch_bounds__(512) void inorm_kernel(const float* __restrict__ Y,
                                                    const float* __restrict__ w,
                                                    const float* __restrict__ bb,
                                                    float* __restrict__ X) {
  int b = blockIdx.x;
  int tid = threadIdx.x;
  int e = tid & 127, sg = tid >> 7;
  __shared__ float ps[4][128], pss[4][128];
  const float* base = Y + (size_t)b * S_ * E_;
  float s = 0.f, ss = 0.f;
  for (int i = sg; i < S_; i += 4) {
    float v = base[(size_t)i * E_ + e];
    s += v; ss += v * v;
  }
  ps[sg][e] = s; pss[sg][e] = ss;
  __syncthreads();
  if (sg == 0) {
    s  = ps[0][e] + ps[1][e] + ps[2][e] + ps[3][e];
    ss = pss[0][e] + pss[1][e] + pss[2][e] + pss[3][e];
    float mean = s / S_;
    float var  = fmaxf(ss / S_ - mean * mean, 0.f);
    float scale = rsqrtf(var + 1e-5f) * w[e];
    ps[0][e]  = scale;
    pss[0][e] = bb[e] - mean * scale;
  }
  __syncthreads();
  float scale = ps[0][e], shift = pss[0][e];
  float* dst = X + (size_t)b * S_ * E_;
  for (int i = sg; i < S_; i += 4) {
    size_t idx = (size_t)i * E_ + e;
    dst[idx] = base[idx] * scale + shift;
  }
}

extern "C" void kernel_launch(void* const* d_in, const int* in_sizes, int n_in,
                              void* d_out, int out_size, void* d_ws, size_t ws_size,
                              hipStream_t stream) {
  const float* depot = (const float*)d_in[0];
  const float* node  = (const float*)d_in[1];
  const float* RA    = (const float*)d_in[2];
  const float* Wd    = (const float*)d_in[3];
  const float* bd    = (const float*)d_in[4];
  const float* Wn    = (const float*)d_in[5];
  const float* bn    = (const float*)d_in[6];
  const float* Wq    = (const float*)d_in[7];
  const float* Wk    = (const float*)d_in[8];
  const float* Wv    = (const float*)d_in[9];
  const float* Wo    = (const float*)d_in[10];
  const float* bo    = (const float*)d_in[11];
  const float* A1w   = (const float*)d_in[12];
  const float* A1b   = (const float*)d_in[13];
  const float* A2w   = (const float*)d_in[14];
  const float* A2b   = (const float*)d_in[15];
  const float* n1w   = (const float*)d_in[16];
  const float* n1b   = (const float*)d_in[17];
  const float* n2w   = (const float*)d_in[18];
  const float* n2b   = (const float*)d_in[19];
  const float* F1w   = (const float*)d_in[20];
  const float* F1b   = (const float*)d_in[21];
  const float* F2w   = (const float*)d_in[22];
  const float* F2b   = (const float*)d_in[23];

  const size_t XSZ  = (size_t)B_ * S_ * E_;
  float* ws = (float*)d_ws;
  float* X   = ws;
  float* Q   = X  + XSZ;
  float* Kb  = Q  + XSZ;
  float* V   = Kb + XSZ;
  float* O   = V  + XSZ;
  float* SC  = O  + XSZ;
  float* TMP = SC;            // aliases SC (SC consumed before TMP written)
  float* HID = SC + XSZ;      // aliases SC tail

  const int M = B_ * S_;

  auto gemm = [&](const float* A, const float* W, const float* bias,
                  const float* res, float* C, int Nn, int K, int relu) {
    dim3 grid(M / 64, Nn / 64);
    gemm_kernel<<<grid, 256, 0, stream>>>(A, W, bias, res, C, M, Nn, K, relu);
  };

  embed_kernel<<<(B_ * S_ * E_ + 255) / 256, 256, 0, stream>>>(depot, node, Wd, bd, Wn, bn, X);

  for (int l = 0; l < L_; ++l) {
    gemm(X, Wq + (size_t)l * E_ * HD_, nullptr, nullptr, Q,  HD_, E_, 0);
    gemm(X, Wk + (size_t)l * E_ * HD_, nullptr, nullptr, Kb, HD_, E_, 0);
    gemm(X, Wv + (size_t)l * E_ * HD_, nullptr, nullptr, V,  HD_, E_, 0);
    score_kernel<<<B_ * H_, 256, 0, stream>>>(Q, Kb, SC);
    attn_kernel<<<B_ * S_, 256, 0, stream>>>(SC, RA,
        A1w + (size_t)l * TWOH_ * TWOH_, A1b + (size_t)l * TWOH_,
        A2w + (size_t)l * TWOH_ * H_,    A2b + (size_t)l * H_, V, O);
    gemm(O, Wo + (size_t)l * HD_ * E_, bo + (size_t)l * E_, X, TMP, E_, HD_, 0);
    inorm_kernel<<<B_, 512, 0, stream>>>(TMP, n1w + (size_t)l * E_, n1b + (size_t)l * E_, X);
    gemm(X, F1w + (size_t)l * E_ * FF_, F1b + (size_t)l * FF_, nullptr, HID, FF_, E_, 1);
    gemm(HID, F2w + (size_t)l * FF_ * E_, F2b + (size_t)l * E_, X, TMP, E_, FF_, 0);
    float* dst = (l == L_ - 1) ? (float*)d_out : X;
    inorm_kernel<<<B_, 512, 0, stream>>>(TMP, n2w + (size_t)l * E_, n2b + (size_t)l * E_, dst);
  }
}

// Round 9
// 2068.049 us; speedup vs baseline: 2.5201x; 1.3212x over previous
//
#include <hip/hip_runtime.h>
#include <hip/hip_bf16.h>

// Problem constants
#define B_   64
#define N_   200
#define S_   201
#define E_   128
#define H_   8
#define D_   16
#define HD_  128
#define FF_  512
#define L_   6
#define TWOH_ 16
#define NCH_  4             // n's per attn block
#define NCHB_ 51            // ceil(S_/NCH_)
#define PADM_ 208           // padded m stride for PL

// ---------------- initial embedding ----------------
__global__ void embed_kernel(const float* __restrict__ depot, const float* __restrict__ node,
                             const float* __restrict__ Wd, const float* __restrict__ bd,
                             const float* __restrict__ Wn, const float* __restrict__ bn,
                             float* __restrict__ X) {
  int idx = blockIdx.x * blockDim.x + threadIdx.x;
  if (idx >= B_ * S_ * E_) return;
  int e  = idx & (E_ - 1);
  int bs = idx >> 7;
  int s  = bs % S_;
  int b  = bs / S_;
  float acc;
  if (s == 0) {
    acc = bd[e];
    #pragma unroll
    for (int i = 0; i < 3; ++i) acc += depot[b * 3 + i] * Wd[i * E_ + e];
  } else {
    acc = bn[e];
    const float* nd = node + ((size_t)b * N_ + (s - 1)) * 4;
    #pragma unroll
    for (int i = 0; i < 4; ++i) acc += nd[i] * Wn[i * E_ + e];
  }
  X[idx] = acc;
}

// ---------------- generic tiled GEMM (f32) ----------------
__global__ __launch_bounds__(256) void gemm_kernel(
    const float* __restrict__ A, const float* __restrict__ W,
    const float* __restrict__ bias, const float* __restrict__ res,
    float* __restrict__ C, int M, int N, int K, int relu) {
  __shared__ float As[64][33];
  __shared__ float Ws[32][64];
  int tid = threadIdx.x;
  int m0 = blockIdx.x * 64;
  int n0 = blockIdx.y * 64;
  int tx = tid & 15, ty = tid >> 4;
  float acc[4][4] = {};
  for (int k0 = 0; k0 < K; k0 += 32) {
    {
      int p = tid * 8;
      int r = p >> 5, c = p & 31;
      const float* src = A + (size_t)(m0 + r) * K + k0 + c;
      #pragma unroll
      for (int i = 0; i < 8; ++i) As[r][c + i] = src[i];
    }
    {
      int p = tid * 8;
      int r = p >> 6, c = p & 63;
      const float* src = W + (size_t)(k0 + r) * N + n0 + c;
      #pragma unroll
      for (int i = 0; i < 8; ++i) Ws[r][c + i] = src[i];
    }
    __syncthreads();
    #pragma unroll
    for (int kk = 0; kk < 32; ++kk) {
      float a[4], w[4];
      #pragma unroll
      for (int i = 0; i < 4; ++i) a[i] = As[ty * 4 + i][kk];
      #pragma unroll
      for (int j = 0; j < 4; ++j) w[j] = Ws[kk][tx * 4 + j];
      #pragma unroll
      for (int i = 0; i < 4; ++i)
        #pragma unroll
        for (int j = 0; j < 4; ++j) acc[i][j] += a[i] * w[j];
    }
    __syncthreads();
  }
  #pragma unroll
  for (int i = 0; i < 4; ++i) {
    int m = m0 + ty * 4 + i;
    #pragma unroll
    for (int j = 0; j < 4; ++j) {
      int n = n0 + tx * 4 + j;
      float v = acc[i][j];
      if (bias) v += bias[n];
      if (res)  v += res[(size_t)m * N + n];
      if (relu) v = v > 0.f ? v : 0.f;
      C[(size_t)m * N + n] = v;
    }
  }
}

// ---------------- attention scores ----------------
__global__ __launch_bounds__(256) void score_kernel(const float* __restrict__ Q,
                                                    const float* __restrict__ Kmat,
                                                    float* __restrict__ SC) {
  int bh = blockIdx.x;
  int h = bh % H_, b = bh / H_;
  __shared__ float qs[S_][D_ + 1];
  __shared__ float ks[S_][D_ + 1];
  int tid = threadIdx.x;
  for (int p = tid; p < S_ * D_; p += 256) {
    int r = p >> 4, d = p & 15;
    size_t g = ((size_t)(b * S_ + r)) * HD_ + h * D_ + d;
    qs[r][d] = Q[g];
    ks[r][d] = Kmat[g];
  }
  __syncthreads();
  float* out = SC + ((size_t)(b * H_ + h)) * S_ * S_;
  for (int p = tid; p < S_ * S_; p += 256) {
    int n = p / S_, m = p - n * S_;
    float acc = 0.f;
    #pragma unroll
    for (int d = 0; d < D_; ++d) acc += qs[n][d] * ks[m][d];
    out[(size_t)n * S_ + m] = acc;
  }
}

// ---------------- fused: edge-MLP + softmax + PV, NCH_ n's per block ----------------
// Weights via uniform scalar loads (SGPR operands). Edge inputs direct from global.
__global__ __launch_bounds__(256) void attn_kernel(
    const float* __restrict__ SC, const float* __restrict__ RA,
    const float* __restrict__ A1w, const float* __restrict__ A1b,
    const float* __restrict__ A2w, const float* __restrict__ A2b,
    const float* __restrict__ V, float* __restrict__ O) {
  int blk = blockIdx.x;
  int b  = blk / NCHB_;
  int n0 = (blk % NCHB_) * NCH_;
  int NV = min(NCH_, S_ - n0);
  __shared__ float PL[NCH_][H_][PADM_];
  __shared__ float partial[2][NCH_][H_][D_];
  __shared__ float inv[NCH_][H_];
  int tid = threadIdx.x;

  // ---- phase 1: edge MLP, one edge at a time per thread, inputs direct from global ----
  for (int e = tid; e < NV * S_; e += 256) {
    int nn = e / S_;
    int m  = e - nn * S_;
    const float* scp = SC + (((size_t)b * H_) * S_ + (n0 + nn)) * S_ + m;
    const float* rap = RA + (((size_t)b * H_) * S_ + (n0 + nn)) * S_ + m;
    float cc[TWOH_];
    #pragma unroll
    for (int h = 0; h < H_; ++h) {
      cc[h]      = scp[(size_t)h * S_ * S_];   // coalesced: consecutive threads -> consecutive m
      cc[H_ + h] = rap[(size_t)h * S_ * S_];
    }
    float h1[TWOH_];
    #pragma unroll
    for (int j = 0; j < TWOH_; ++j) h1[j] = A1b[j];        // uniform -> s_load
    #pragma unroll
    for (int i = 0; i < TWOH_; ++i) {
      float c = cc[i];
      #pragma unroll
      for (int j = 0; j < TWOH_; ++j)
        h1[j] += c * A1w[i * TWOH_ + j];                   // uniform -> SGPR operand
    }
    float agg[H_];
    #pragma unroll
    for (int h = 0; h < H_; ++h) agg[h] = A2b[h];
    #pragma unroll
    for (int j = 0; j < TWOH_; ++j) {
      float r = fmaxf(h1[j], 0.f);
      #pragma unroll
      for (int h = 0; h < H_; ++h)
        agg[h] += r * A2w[j * H_ + h];
    }
    #pragma unroll
    for (int h = 0; h < H_; ++h) PL[nn][h][m] = agg[h];
  }
  __syncthreads();

  // ---- phase 2: softmax over m; 32 groups (nn,h) x 8 lanes ----
  {
    int g = tid >> 3, lane = tid & 7;
    int nn = g >> 3, h = g & 7;
    if (nn < NV) {
      float mx = -1e30f;
      for (int m = lane; m < S_; m += 8) mx = fmaxf(mx, PL[nn][h][m]);
      #pragma unroll
      for (int off = 4; off > 0; off >>= 1) mx = fmaxf(mx, __shfl_xor(mx, off, 8));
      float sum = 0.f;
      for (int m = lane; m < S_; m += 8) {
        float e = __expf(PL[nn][h][m] - mx);
        PL[nn][h][m] = e;
        sum += e;
      }
      #pragma unroll
      for (int off = 4; off > 0; off >>= 1) sum += __shfl_xor(sum, off, 8);
      if (lane == 0) inv[nn][h] = 1.f / sum;
    }
  }
  __syncthreads();

  // ---- phase 3: PV, all 256 threads: (m-parity) x (h,d), 4 n-accumulators per V load ----
  {
    int half = tid >> 7, h = (tid >> 4) & 7, d = tid & 15;
    float a0 = 0.f, a1 = 0.f, a2 = 0.f, a3 = 0.f;
    const float* vp = V + (size_t)b * S_ * HD_ + h * D_ + d;
    for (int m = half; m < S_; m += 2) {
      float vv = vp[(size_t)m * HD_];
      a0 += PL[0][h][m] * vv;
      a1 += PL[1][h][m] * vv;
      a2 += PL[2][h][m] * vv;
      a3 += PL[3][h][m] * vv;
    }
    partial[half][0][h][d] = a0;
    partial[half][1][h][d] = a1;
    partial[half][2][h][d] = a2;
    partial[half][3][h][d] = a3;
  }
  __syncthreads();
  if (tid < 128) {
    int h = tid >> 4, d = tid & 15;
    #pragma unroll
    for (int nn = 0; nn < NCH_; ++nn)
      if (nn < NV) {
        float s = (partial[0][nn][h][d] + partial[1][nn][h][d]) * inv[nn][h];
        O[((size_t)b * S_ + (n0 + nn)) * HD_ + h * D_ + d] = s;
      }
  }
}

// ---------------- instance norm over sequence axis ----------------
__global__ __launch_bounds__(512) void inorm_kernel(const float* __restrict__ Y,
                                                    const float* __restrict__ w,
                                                    const float* __restrict__ bb,
                                                    float* __restrict__ X) {
  int b = blockIdx.x;
  int tid = threadIdx.x;
  int e = tid & 127, sg = tid >> 7;
  __shared__ float ps[4][128], pss[4][128];
  const float* base = Y + (size_t)b * S_ * E_;
  float s = 0.f, ss = 0.f;
  for (int i = sg; i < S_; i += 4) {
    float v = base[(size_t)i * E_ + e];
    s += v; ss += v * v;
  }
  ps[sg][e] = s; pss[sg][e] = ss;
  __syncthreads();
  if (sg == 0) {
    s  = ps[0][e] + ps[1][e] + ps[2][e] + ps[3][e];
    ss = pss[0][e] + pss[1][e] + pss[2][e] + pss[3][e];
    float mean = s / S_;
    float var  = fmaxf(ss / S_ - mean * mean, 0.f);
    float scale = rsqrtf(var + 1e-5f) * w[e];
    ps[0][e]  = scale;
    pss[0][e] = bb[e] - mean * scale;
  }
  __syncthreads();
  float scale = ps[0][e], shift = pss[0][e];
  float* dst = X + (size_t)b * S_ * E_;
  for (int i = sg; i < S_; i += 4) {
    size_t idx = (size_t)i * E_ + e;
    dst[idx] = base[idx] * scale + shift;
  }
}

extern "C" void kernel_launch(void* const* d_in, const int* in_sizes, int n_in,
                              void* d_out, int out_size, void* d_ws, size_t ws_size,
                              hipStream_t stream) {
  const float* depot = (const float*)d_in[0];
  const float* node  = (const float*)d_in[1];
  const float* RA    = (const float*)d_in[2];
  const float* Wd    = (const float*)d_in[3];
  const float* bd    = (const float*)d_in[4];
  const float* Wn    = (const float*)d_in[5];
  const float* bn    = (const float*)d_in[6];
  const float* Wq    = (const float*)d_in[7];
  const float* Wk    = (const float*)d_in[8];
  const float* Wv    = (const float*)d_in[9];
  const float* Wo    = (const float*)d_in[10];
  const float* bo    = (const float*)d_in[11];
  const float* A1w   = (const float*)d_in[12];
  const float* A1b   = (const float*)d_in[13];
  const float* A2w   = (const float*)d_in[14];
  const float* A2b   = (const float*)d_in[15];
  const float* n1w   = (const float*)d_in[16];
  const float* n1b   = (const float*)d_in[17];
  const float* n2w   = (const float*)d_in[18];
  const float* n2b   = (const float*)d_in[19];
  const float* F1w   = (const float*)d_in[20];
  const float* F1b   = (const float*)d_in[21];
  const float* F2w   = (const float*)d_in[22];
  const float* F2b   = (const float*)d_in[23];

  const size_t XSZ  = (size_t)B_ * S_ * E_;
  float* ws = (float*)d_ws;
  float* X   = ws;
  float* Q   = X  + XSZ;
  float* Kb  = Q  + XSZ;
  float* V   = Kb + XSZ;
  float* O   = V  + XSZ;
  float* SC  = O  + XSZ;
  float* TMP = SC;            // aliases SC (SC consumed before TMP written)
  float* HID = SC + XSZ;      // aliases SC tail

  const int M = B_ * S_;

  auto gemm = [&](const float* A, const float* W, const float* bias,
                  const float* res, float* C, int Nn, int K, int relu) {
    dim3 grid(M / 64, Nn / 64);
    gemm_kernel<<<grid, 256, 0, stream>>>(A, W, bias, res, C, M, Nn, K, relu);
  };

  embed_kernel<<<(B_ * S_ * E_ + 255) / 256, 256, 0, stream>>>(depot, node, Wd, bd, Wn, bn, X);

  for (int l = 0; l < L_; ++l) {
    gemm(X, Wq + (size_t)l * E_ * HD_, nullptr, nullptr, Q,  HD_, E_, 0);
    gemm(X, Wk + (size_t)l * E_ * HD_, nullptr, nullptr, Kb, HD_, E_, 0);
    gemm(X, Wv + (size_t)l * E_ * HD_, nullptr, nullptr, V,  HD_, E_, 0);
    score_kernel<<<B_ * H_, 256, 0, stream>>>(Q, Kb, SC);
    attn_kernel<<<B_ * NCHB_, 256, 0, stream>>>(SC, RA,
        A1w + (size_t)l * TWOH_ * TWOH_, A1b + (size_t)l * TWOH_,
        A2w + (size_t)l * TWOH_ * H_,    A2b + (size_t)l * H_, V, O);
    gemm(O, Wo + (size_t)l * HD_ * E_, bo + (size_t)l * E_, X, TMP, E_, HD_, 0);
    inorm_kernel<<<B_, 512, 0, stream>>>(TMP, n1w + (size_t)l * E_, n1b + (size_t)l * E_, X);
    gemm(X, F1w + (size_t)l * E_ * FF_, F1b + (size_t)l * FF_, nullptr, HID, FF_, E_, 1);
    gemm(HID, F2w + (size_t)l * FF_ * E_, F2b + (size_t)l * E_, X, TMP, E_, FF_, 0);
    float* dst = (l == L_ - 1) ? (float*)d_out : X;
    inorm_kernel<<<B_, 512, 0, stream>>>(TMP, n2w + (size_t)l * E_, n2b + (size_t)l * E_, dst);
  }
}

// Round 11
// 1798.489 us; speedup vs baseline: 2.8978x; 1.1499x over previous
//
#include <hip/hip_runtime.h>
#include <hip/hip_bf16.h>

// Problem constants
#define B_   64
#define N_   200
#define S_   201
#define E_   128
#define H_   8
#define D_   16
#define HD_  128
#define FF_  512
#define L_   6
#define TWOH_ 16
#define NCH_  4             // n's per attn block
#define NCHB_ 51            // ceil(S_/NCH_)
#define PADM_ 208           // padded m stride for PL

typedef __hip_bfloat16 bf16;
typedef __attribute__((ext_vector_type(8))) short bfrag;   // 8 bf16 = 4 VGPRs
typedef __attribute__((ext_vector_type(4))) float f32x4;

__device__ __forceinline__ void split_bf16(float v, bf16& h, bf16& l) {
  h = __float2bfloat16(v);
  l = __float2bfloat16(v - __bfloat162float(h));
}

// ---------------- initial embedding ----------------
__global__ void embed_kernel(const float* __restrict__ depot, const float* __restrict__ node,
                             const float* __restrict__ Wd, const float* __restrict__ bd,
                             const float* __restrict__ Wn, const float* __restrict__ bn,
                             float* __restrict__ X) {
  int idx = blockIdx.x * blockDim.x + threadIdx.x;
  if (idx >= B_ * S_ * E_) return;
  int e  = idx & (E_ - 1);
  int bs = idx >> 7;
  int s  = bs % S_;
  int b  = bs / S_;
  float acc;
  if (s == 0) {
    acc = bd[e];
    #pragma unroll
    for (int i = 0; i < 3; ++i) acc += depot[b * 3 + i] * Wd[i * E_ + e];
  } else {
    acc = bn[e];
    const float* nd = node + ((size_t)b * N_ + (s - 1)) * 4;
    #pragma unroll
    for (int i = 0; i < 4; ++i) acc += nd[i] * Wn[i * E_ + e];
  }
  X[idx] = acc;
}

// ---------------- weight transpose+convert to split bf16 (once per launch) ----------------
// layout (bf16 units): WoT 6x[128][128] @0 ; F1T 6x[512][128] @98304 ; F2T 6x[128][512] @491520
__global__ void wcvt_kernel(const float* __restrict__ Wo, const float* __restrict__ F1w,
                            const float* __restrict__ F2w,
                            bf16* __restrict__ WTh, bf16* __restrict__ WTl) {
  int idx = blockIdx.x * blockDim.x + threadIdx.x;
  if (idx >= 884736) return;
  float v;
  if (idx < 98304) {
    int l = idx / 16384, rr = idx % 16384;
    int e = rr / 128, h = rr % 128;
    v = Wo[(size_t)l * 16384 + h * 128 + e];
  } else if (idx < 491520) {
    int rem = idx - 98304;
    int l = rem / 65536, rr = rem % 65536;
    int f = rr / 128, e = rr % 128;
    v = F1w[(size_t)l * 65536 + e * 512 + f];
  } else {
    int rem = idx - 491520;
    int l = rem / 65536, rr = rem % 65536;
    int e = rr / 512, f = rr % 512;
    v = F2w[(size_t)l * 65536 + f * 128 + e];
  }
  bf16 h, l2;
  split_bf16(v, h, l2);
  WTh[idx] = h;
  WTl[idx] = l2;
}

// ---------------- generic tiled GEMM (f32) — QKV only ----------------
__global__ __launch_bounds__(256) void gemm_kernel(
    const float* __restrict__ A, const float* __restrict__ W,
    const float* __restrict__ bias, const float* __restrict__ res,
    float* __restrict__ C, int M, int N, int K, int relu) {
  __shared__ float As[64][33];
  __shared__ float Ws[32][64];
  int tid = threadIdx.x;
  int m0 = blockIdx.x * 64;
  int n0 = blockIdx.y * 64;
  int tx = tid & 15, ty = tid >> 4;
  float acc[4][4] = {};
  for (int k0 = 0; k0 < K; k0 += 32) {
    {
      int p = tid * 8;
      int r = p >> 5, c = p & 31;
      const float* src = A + (size_t)(m0 + r) * K + k0 + c;
      #pragma unroll
      for (int i = 0; i < 8; ++i) As[r][c + i] = src[i];
    }
    {
      int p = tid * 8;
      int r = p >> 6, c = p & 63;
      const float* src = W + (size_t)(k0 + r) * N + n0 + c;
      #pragma unroll
      for (int i = 0; i < 8; ++i) Ws[r][c + i] = src[i];
    }
    __syncthreads();
    #pragma unroll
    for (int kk = 0; kk < 32; ++kk) {
      float a[4], w[4];
      #pragma unroll
      for (int i = 0; i < 4; ++i) a[i] = As[ty * 4 + i][kk];
      #pragma unroll
      for (int j = 0; j < 4; ++j) w[j] = Ws[kk][tx * 4 + j];
      #pragma unroll
      for (int i = 0; i < 4; ++i)
        #pragma unroll
        for (int j = 0; j < 4; ++j) acc[i][j] += a[i] * w[j];
    }
    __syncthreads();
  }
  #pragma unroll
  for (int i = 0; i < 4; ++i) {
    int m = m0 + ty * 4 + i;
    #pragma unroll
    for (int j = 0; j < 4; ++j) {
      int n = n0 + tx * 4 + j;
      float v = acc[i][j];
      if (bias) v += bias[n];
      if (res)  v += res[(size_t)m * N + n];
      if (relu) v = v > 0.f ? v : 0.f;
      C[(size_t)m * N + n] = v;
    }
  }
}

// ---------------- split-precision MFMA GEMM ----------------
// Computes C = A@B (+bias)(+res) with A = Ah+Al, B^T rows = BTh+BTl (bf16 hi/lo pairs).
// acc += ah*bh + ah*bl + al*bh  (al*bl dropped, ~2^-18 rel)
// EPI 1: f32 out (bias+res). EPI 2: relu(bias) -> split bf16 out.
template<int EPI>
__global__ __launch_bounds__(256) void mgemm_kernel(
    const bf16* __restrict__ Ah, const bf16* __restrict__ Al,
    const bf16* __restrict__ BTh, const bf16* __restrict__ BTl,
    const float* __restrict__ bias, const float* __restrict__ res,
    float* __restrict__ Cf, bf16* __restrict__ Cbh, bf16* __restrict__ Cbl,
    int K, int Ntot) {
  __shared__ __align__(16) bf16 Ash[64][72];
  __shared__ __align__(16) bf16 Asl[64][72];
  __shared__ __align__(16) bf16 Bsh[64][72];
  __shared__ __align__(16) bf16 Bsl[64][72];
  int tid = threadIdx.x;
  int m0 = blockIdx.x * 64, n0 = blockIdx.y * 64;
  int lane = tid & 63, wave = tid >> 6;
  int wr = wave >> 1, wc = wave & 1;
  int la = lane & 15, lb = lane >> 4;
  f32x4 acc[2][2] = {};
  for (int k0 = 0; k0 < K; k0 += 64) {
    #pragma unroll
    for (int p = 0; p < 2; ++p) {
      int ch = tid + p * 256;
      int r = ch >> 3, kc = (ch & 7) << 3;
      size_t ga = (size_t)(m0 + r) * K + k0 + kc;
      size_t gb = (size_t)(n0 + r) * K + k0 + kc;
      *reinterpret_cast<bfrag*>(&Ash[r][kc]) = *reinterpret_cast<const bfrag*>(&Ah[ga]);
      *reinterpret_cast<bfrag*>(&Asl[r][kc]) = *reinterpret_cast<const bfrag*>(&Al[ga]);
      *reinterpret_cast<bfrag*>(&Bsh[r][kc]) = *reinterpret_cast<const bfrag*>(&BTh[gb]);
      *reinterpret_cast<bfrag*>(&Bsl[r][kc]) = *reinterpret_cast<const bfrag*>(&BTl[gb]);
    }
    __syncthreads();
    #pragma unroll
    for (int ks = 0; ks < 64; ks += 32) {
      bfrag ah0 = *(const bfrag*)&Ash[wr * 32 + la][ks + lb * 8];
      bfrag ah1 = *(const bfrag*)&Ash[wr * 32 + 16 + la][ks + lb * 8];
      bfrag al0 = *(const bfrag*)&Asl[wr * 32 + la][ks + lb * 8];
      bfrag al1 = *(const bfrag*)&Asl[wr * 32 + 16 + la][ks + lb * 8];
      bfrag bh0 = *(const bfrag*)&Bsh[wc * 32 + la][ks + lb * 8];
      bfrag bh1 = *(const bfrag*)&Bsh[wc * 32 + 16 + la][ks + lb * 8];
      bfrag bl0 = *(const bfrag*)&Bsl[wc * 32 + la][ks + lb * 8];
      bfrag bl1 = *(const bfrag*)&Bsl[wc * 32 + 16 + la][ks + lb * 8];
      acc[0][0] = __builtin_amdgcn_mfma_f32_16x16x32_bf16(ah0, bh0, acc[0][0], 0, 0, 0);
      acc[0][0] = __builtin_amdgcn_mfma_f32_16x16x32_bf16(ah0, bl0, acc[0][0], 0, 0, 0);
      acc[0][0] = __builtin_amdgcn_mfma_f32_16x16x32_bf16(al0, bh0, acc[0][0], 0, 0, 0);
      acc[0][1] = __builtin_amdgcn_mfma_f32_16x16x32_bf16(ah0, bh1, acc[0][1], 0, 0, 0);
      acc[0][1] = __builtin_amdgcn_mfma_f32_16x16x32_bf16(ah0, bl1, acc[0][1], 0, 0, 0);
      acc[0][1] = __builtin_amdgcn_mfma_f32_16x16x32_bf16(al0, bh1, acc[0][1], 0, 0, 0);
      acc[1][0] = __builtin_amdgcn_mfma_f32_16x16x32_bf16(ah1, bh0, acc[1][0], 0, 0, 0);
      acc[1][0] = __builtin_amdgcn_mfma_f32_16x16x32_bf16(ah1, bl0, acc[1][0], 0, 0, 0);
      acc[1][0] = __builtin_amdgcn_mfma_f32_16x16x32_bf16(al1, bh0, acc[1][0], 0, 0, 0);
      acc[1][1] = __builtin_amdgcn_mfma_f32_16x16x32_bf16(ah1, bh1, acc[1][1], 0, 0, 0);
      acc[1][1] = __builtin_amdgcn_mfma_f32_16x16x32_bf16(ah1, bl1, acc[1][1], 0, 0, 0);
      acc[1][1] = __builtin_amdgcn_mfma_f32_16x16x32_bf16(al1, bh1, acc[1][1], 0, 0, 0);
    }
    __syncthreads();
  }
  // epilogue: C/D layout col=lane&15, row=(lane>>4)*4+j  [m89-verified]
  int r0 = lb * 4;
  #pragma unroll
  for (int ti = 0; ti < 2; ++ti)
    #pragma unroll
    for (int tj = 0; tj < 2; ++tj)
      #pragma unroll
      for (int j = 0; j < 4; ++j) {
        int m = m0 + wr * 32 + ti * 16 + r0 + j;
        int n = n0 + wc * 32 + tj * 16 + la;
        float v = acc[ti][tj][j];
        if (EPI == 1) {
          v += bias[n] + res[(size_t)m * Ntot + n];
          Cf[(size_t)m * Ntot + n] = v;
        } else {
          v += bias[n];
          v = v > 0.f ? v : 0.f;
          bf16 vh, vl;
          split_bf16(v, vh, vl);
          Cbh[(size_t)m * Ntot + n] = vh;
          Cbl[(size_t)m * Ntot + n] = vl;
        }
      }
}

// ---------------- attention scores ----------------
__global__ __launch_bounds__(256) void score_kernel(const float* __restrict__ Q,
                                                    const float* __restrict__ Kmat,
                                                    float* __restrict__ SC) {
  int bh = blockIdx.x;
  int h = bh % H_, b = bh / H_;
  __shared__ float qs[S_][D_ + 1];
  __shared__ float ks[S_][D_ + 1];
  int tid = threadIdx.x;
  for (int p = tid; p < S_ * D_; p += 256) {
    int r = p >> 4, d = p & 15;
    size_t g = ((size_t)(b * S_ + r)) * HD_ + h * D_ + d;
    qs[r][d] = Q[g];
    ks[r][d] = Kmat[g];
  }
  __syncthreads();
  float* out = SC + ((size_t)(b * H_ + h)) * S_ * S_;
  for (int p = tid; p < S_ * S_; p += 256) {
    int n = p / S_, m = p - n * S_;
    float acc = 0.f;
    #pragma unroll
    for (int d = 0; d < D_; ++d) acc += qs[n][d] * ks[m][d];
    out[(size_t)n * S_ + m] = acc;
  }
}

// ---------------- fused: edge-MLP + softmax + PV, NCH_ n's per block ----------------
__global__ __launch_bounds__(256) void attn_kernel(
    const float* __restrict__ SC, const float* __restrict__ RA,
    const float* __restrict__ A1w, const float* __restrict__ A1b,
    const float* __restrict__ A2w, const float* __restrict__ A2b,
    const float* __restrict__ V, bf16* __restrict__ OBh, bf16* __restrict__ OBl) {
  int blk = blockIdx.x;
  int b  = blk / NCHB_;
  int n0 = (blk % NCHB_) * NCH_;
  int NV = min(NCH_, S_ - n0);
  __shared__ float PL[NCH_][H_][PADM_];
  __shared__ float partial[2][NCH_][H_][D_];
  __shared__ float inv[NCH_][H_];
  int tid = threadIdx.x;

  // phase 1: edge MLP, weights via uniform scalar loads
  for (int e = tid; e < NV * S_; e += 256) {
    int nn = e / S_;
    int m  = e - nn * S_;
    const float* scp = SC + (((size_t)b * H_) * S_ + (n0 + nn)) * S_ + m;
    const float* rap = RA + (((size_t)b * H_) * S_ + (n0 + nn)) * S_ + m;
    float cc[TWOH_];
    #pragma unroll
    for (int h = 0; h < H_; ++h) {
      cc[h]      = scp[(size_t)h * S_ * S_];
      cc[H_ + h] = rap[(size_t)h * S_ * S_];
    }
    float h1[TWOH_];
    #pragma unroll
    for (int j = 0; j < TWOH_; ++j) h1[j] = A1b[j];
    #pragma unroll
    for (int i = 0; i < TWOH_; ++i) {
      float c = cc[i];
      #pragma unroll
      for (int j = 0; j < TWOH_; ++j)
        h1[j] += c * A1w[i * TWOH_ + j];
    }
    float agg[H_];
    #pragma unroll
    for (int h = 0; h < H_; ++h) agg[h] = A2b[h];
    #pragma unroll
    for (int j = 0; j < TWOH_; ++j) {
      float r = fmaxf(h1[j], 0.f);
      #pragma unroll
      for (int h = 0; h < H_; ++h)
        agg[h] += r * A2w[j * H_ + h];
    }
    #pragma unroll
    for (int h = 0; h < H_; ++h) PL[nn][h][m] = agg[h];
  }
  __syncthreads();

  // phase 2: softmax over m; 32 groups (nn,h) x 8 lanes
  {
    int g = tid >> 3, lane = tid & 7;
    int nn = g >> 3, h = g & 7;
    if (nn < NV) {
      float mx = -1e30f;
      for (int m = lane; m < S_; m += 8) mx = fmaxf(mx, PL[nn][h][m]);
      #pragma unroll
      for (int off = 4; off > 0; off >>= 1) mx = fmaxf(mx, __shfl_xor(mx, off, 8));
      float sum = 0.f;
      for (int m = lane; m < S_; m += 8) {
        float e = __expf(PL[nn][h][m] - mx);
        PL[nn][h][m] = e;
        sum += e;
      }
      #pragma unroll
      for (int off = 4; off > 0; off >>= 1) sum += __shfl_xor(sum, off, 8);
      if (lane == 0) inv[nn][h] = 1.f / sum;
    }
  }
  __syncthreads();

  // phase 3: PV
  {
    int half = tid >> 7, h = (tid >> 4) & 7, d = tid & 15;
    float a0 = 0.f, a1 = 0.f, a2 = 0.f, a3 = 0.f;
    const float* vp = V + (size_t)b * S_ * HD_ + h * D_ + d;
    for (int m = half; m < S_; m += 2) {
      float vv = vp[(size_t)m * HD_];
      a0 += PL[0][h][m] * vv;
      a1 += PL[1][h][m] * vv;
      a2 += PL[2][h][m] * vv;
      a3 += PL[3][h][m] * vv;
    }
    partial[half][0][h][d] = a0;
    partial[half][1][h][d] = a1;
    partial[half][2][h][d] = a2;
    partial[half][3][h][d] = a3;
  }
  __syncthreads();
  if (tid < 128) {
    int h = tid >> 4, d = tid & 15;
    #pragma unroll
    for (int nn = 0; nn < NCH_; ++nn)
      if (nn < NV) {
        float s = (partial[0][nn][h][d] + partial[1][nn][h][d]) * inv[nn][h];
        size_t o = ((size_t)b * S_ + (n0 + nn)) * HD_ + h * D_ + d;
        bf16 sh, sl;
        split_bf16(s, sh, sl);
        OBh[o] = sh;
        OBl[o] = sl;
      }
  }
}

// ---------------- instance norm (optional split-bf16 shadow output) ----------------
__global__ __launch_bounds__(512) void inorm_kernel(const float* __restrict__ Y,
                                                    const float* __restrict__ w,
                                                    const float* __restrict__ bb,
                                                    float* __restrict__ X,
                                                    bf16* __restrict__ XBh,
                                                    bf16* __restrict__ XBl) {
  int b = blockIdx.x;
  int tid = threadIdx.x;
  int e = tid & 127, sg = tid >> 7;
  __shared__ float ps[4][128], pss[4][128];
  const float* base = Y + (size_t)b * S_ * E_;
  float s = 0.f, ss = 0.f;
  for (int i = sg; i < S_; i += 4) {
    float v = base[(size_t)i * E_ + e];
    s += v; ss += v * v;
  }
  ps[sg][e] = s; pss[sg][e] = ss;
  __syncthreads();
  if (sg == 0) {
    s  = ps[0][e] + ps[1][e] + ps[2][e] + ps[3][e];
    ss = pss[0][e] + pss[1][e] + pss[2][e] + pss[3][e];
    float mean = s / S_;
    float var  = fmaxf(ss / S_ - mean * mean, 0.f);
    float scale = rsqrtf(var + 1e-5f) * w[e];
    ps[0][e]  = scale;
    pss[0][e] = bb[e] - mean * scale;
  }
  __syncthreads();
  float scale = ps[0][e], shift = pss[0][e];
  float* dst = X + (size_t)b * S_ * E_;
  for (int i = sg; i < S_; i += 4) {
    size_t idx = (size_t)i * E_ + e;
    float v = base[idx] * scale + shift;
    dst[idx] = v;
    if (XBh) {
      size_t gi = (size_t)b * S_ * E_ + idx;
      bf16 vh, vl;
      split_bf16(v, vh, vl);
      XBh[gi] = vh;
      XBl[gi] = vl;
    }
  }
}

extern "C" void kernel_launch(void* const* d_in, const int* in_sizes, int n_in,
                              void* d_out, int out_size, void* d_ws, size_t ws_size,
                              hipStream_t stream) {
  const float* depot = (const float*)d_in[0];
  const float* node  = (const float*)d_in[1];
  const float* RA    = (const float*)d_in[2];
  const float* Wd    = (const float*)d_in[3];
  const float* bd    = (const float*)d_in[4];
  const float* Wn    = (const float*)d_in[5];
  const float* bn    = (const float*)d_in[6];
  const float* Wq    = (const float*)d_in[7];
  const float* Wk    = (const float*)d_in[8];
  const float* Wv    = (const float*)d_in[9];
  const float* Wo    = (const float*)d_in[10];
  const float* bo    = (const float*)d_in[11];
  const float* A1w   = (const float*)d_in[12];
  const float* A1b   = (const float*)d_in[13];
  const float* A2w   = (const float*)d_in[14];
  const float* A2b   = (const float*)d_in[15];
  const float* n1w   = (const float*)d_in[16];
  const float* n1b   = (const float*)d_in[17];
  const float* n2w   = (const float*)d_in[18];
  const float* n2b   = (const float*)d_in[19];
  const float* F1w   = (const float*)d_in[20];
  const float* F1b   = (const float*)d_in[21];
  const float* F2w   = (const float*)d_in[22];
  const float* F2b   = (const float*)d_in[23];

  const size_t XSZ  = (size_t)B_ * S_ * E_;        // 1,646,592
  const size_t SCSZ = (size_t)B_ * H_ * S_ * S_;   // 20,685,312
  const size_t XBF  = XSZ / 2;                     // bf16 buffer in float-slots: 823,296
  float* ws = (float*)d_ws;
  float* X   = ws;                    // f32 [M][E]
  float* Q   = ws + XSZ;              // f32 [M][HD]; reused as OBh after score
  float* Kb  = ws + 2 * XSZ;          //              reused as OBl after score
  float* V   = ws + 3 * XSZ;
  float* SC  = ws + 4 * XSZ;          // SCSZ region, multi-purpose after attn:
  float* TMP = SC;                                   // f32 [0, XSZ)
  bf16*  XBh = (bf16*)(SC + XSZ);                    // M*E bf16
  bf16*  XBl = (bf16*)(SC + XSZ + XBF);
  bf16*  HBh = (bf16*)(SC + XSZ + 2 * XBF);          // M*FF bf16 (3,293,184 fl... as 2 slots of 4*XBF)
  bf16*  HBl = (bf16*)(SC + XSZ + 2 * XBF + 4 * XBF);
  float* tail = ws + 4 * XSZ + SCSZ;
  bf16*  WTh = (bf16*)tail;                          // 884,736 bf16 = 442,368 fl
  bf16*  WTl = (bf16*)(tail + 442368);
  // ws use: 4*XSZ + SCSZ + 884,736 floats = 28,156,416 fl = 112.6 MB
  bf16* OBh = (bf16*)Q;
  bf16* OBl = (bf16*)Kb;

  const int M = B_ * S_;  // 12864 = 201*64

  auto gemm = [&](const float* A, const float* W, const float* bias,
                  const float* res, float* C, int Nn, int K, int relu) {
    dim3 grid(M / 64, Nn / 64);
    gemm_kernel<<<grid, 256, 0, stream>>>(A, W, bias, res, C, M, Nn, K, relu);
  };

  wcvt_kernel<<<3456, 256, 0, stream>>>(Wo, F1w, F2w, WTh, WTl);
  embed_kernel<<<(B_ * S_ * E_ + 255) / 256, 256, 0, stream>>>(depot, node, Wd, bd, Wn, bn, X);

  for (int l = 0; l < L_; ++l) {
    gemm(X, Wq + (size_t)l * E_ * HD_, nullptr, nullptr, Q,  HD_, E_, 0);
    gemm(X, Wk + (size_t)l * E_ * HD_, nullptr, nullptr, Kb, HD_, E_, 0);
    gemm(X, Wv + (size_t)l * E_ * HD_, nullptr, nullptr, V,  HD_, E_, 0);
    score_kernel<<<B_ * H_, 256, 0, stream>>>(Q, Kb, SC);
    attn_kernel<<<B_ * NCHB_, 256, 0, stream>>>(SC, RA,
        A1w + (size_t)l * TWOH_ * TWOH_, A1b + (size_t)l * TWOH_,
        A2w + (size_t)l * TWOH_ * H_,    A2b + (size_t)l * H_, V, OBh, OBl);
    // Wo: TMP = OB @ WoT^T + bo + X   (split precision)
    mgemm_kernel<1><<<dim3(M / 64, 2), 256, 0, stream>>>(
        OBh, OBl, WTh + (size_t)l * 16384, WTl + (size_t)l * 16384,
        bo + (size_t)l * E_, X, TMP, nullptr, nullptr, HD_, E_);
    inorm_kernel<<<B_, 512, 0, stream>>>(TMP, n1w + (size_t)l * E_, n1b + (size_t)l * E_, X, XBh, XBl);
    // F1: HB = relu(XB @ F1T^T + F1b)  (split bf16 out)
    mgemm_kernel<2><<<dim3(M / 64, 8), 256, 0, stream>>>(
        XBh, XBl, WTh + 98304 + (size_t)l * 65536, WTl + 98304 + (size_t)l * 65536,
        F1b + (size_t)l * FF_, nullptr, nullptr, HBh, HBl, E_, FF_);
    // F2: TMP = HB @ F2T^T + F2b + X
    mgemm_kernel<1><<<dim3(M / 64, 2), 256, 0, stream>>>(
        HBh, HBl, WTh + 491520 + (size_t)l * 65536, WTl + 491520 + (size_t)l * 65536,
        F2b + (size_t)l * E_, X, TMP, nullptr, nullptr, FF_, E_);
    float* dst = (l == L_ - 1) ? (float*)d_out : X;
    inorm_kernel<<<B_, 512, 0, stream>>>(TMP, n2w + (size_t)l * E_, n2b + (size_t)l * E_, dst, nullptr, nullptr);
  }
}

// Round 12
// 1599.512 us; speedup vs baseline: 3.2583x; 1.1244x over previous
//
#include <hip/hip_runtime.h>
#include <hip/hip_bf16.h>

// Problem constants
#define B_   64
#define N_   200
#define S_   201
#define E_   128
#define H_   8
#define D_   16
#define HD_  128
#define FF_  512
#define L_   6
#define TWOH_ 16
#define NCH_  4             // n's per attn block
#define NCHB_ 51            // ceil(S_/NCH_)
#define PADM_ 208           // padded m stride for PL

typedef __hip_bfloat16 bf16;
typedef __attribute__((ext_vector_type(8))) short bfrag;   // 8 bf16 = 4 VGPRs
typedef __attribute__((ext_vector_type(4))) float f32x4;

__device__ __forceinline__ void split_bf16(float v, bf16& h, bf16& l) {
  h = __float2bfloat16(v);
  l = __float2bfloat16(v - __bfloat162float(h));
}

// ---------------- initial embedding (also emits split-bf16 shadow for QKV mgemm) ----------------
__global__ void embed_kernel(const float* __restrict__ depot, const float* __restrict__ node,
                             const float* __restrict__ Wd, const float* __restrict__ bd,
                             const float* __restrict__ Wn, const float* __restrict__ bn,
                             float* __restrict__ X, bf16* __restrict__ XBh, bf16* __restrict__ XBl) {
  int idx = blockIdx.x * blockDim.x + threadIdx.x;
  if (idx >= B_ * S_ * E_) return;
  int e  = idx & (E_ - 1);
  int bs = idx >> 7;
  int s  = bs % S_;
  int b  = bs / S_;
  float acc;
  if (s == 0) {
    acc = bd[e];
    #pragma unroll
    for (int i = 0; i < 3; ++i) acc += depot[b * 3 + i] * Wd[i * E_ + e];
  } else {
    acc = bn[e];
    const float* nd = node + ((size_t)b * N_ + (s - 1)) * 4;
    #pragma unroll
    for (int i = 0; i < 4; ++i) acc += nd[i] * Wn[i * E_ + e];
  }
  X[idx] = acc;
  bf16 hh, ll;
  split_bf16(acc, hh, ll);
  XBh[idx] = hh;
  XBl[idx] = ll;
}

// ---------------- weight transpose+convert to split bf16 (once per launch) ----------------
// layout (bf16 units): WoT 6x[128][128] @0 ; F1T 6x[512][128] @98304 ; F2T 6x[128][512] @491520
// WqT 6x[128][128] @884736 ; WkT @983040 ; WvT @1081344 ; total 1179648
__global__ void wcvt_kernel(const float* __restrict__ Wo, const float* __restrict__ F1w,
                            const float* __restrict__ F2w, const float* __restrict__ Wq,
                            const float* __restrict__ Wk, const float* __restrict__ Wv,
                            bf16* __restrict__ WTh, bf16* __restrict__ WTl) {
  int idx = blockIdx.x * blockDim.x + threadIdx.x;
  if (idx >= 1179648) return;
  float v;
  if (idx < 98304) {
    int l = idx / 16384, rr = idx % 16384;
    int e = rr / 128, h = rr % 128;
    v = Wo[(size_t)l * 16384 + h * 128 + e];
  } else if (idx < 491520) {
    int rem = idx - 98304;
    int l = rem / 65536, rr = rem % 65536;
    int f = rr / 128, e = rr % 128;
    v = F1w[(size_t)l * 65536 + e * 512 + f];
  } else if (idx < 884736) {
    int rem = idx - 491520;
    int l = rem / 65536, rr = rem % 65536;
    int e = rr / 512, f = rr % 512;
    v = F2w[(size_t)l * 65536 + f * 128 + e];
  } else {
    const float* src = (idx < 983040) ? Wq : (idx < 1081344) ? Wk : Wv;
    int rem = idx - ((idx < 983040) ? 884736 : (idx < 1081344) ? 983040 : 1081344);
    int l = rem / 16384, rr = rem % 16384;
    int hd = rr / 128, e = rr % 128;
    v = src[(size_t)l * 16384 + e * 128 + hd];
  }
  bf16 h, l2;
  split_bf16(v, h, l2);
  WTh[idx] = h;
  WTl[idx] = l2;
}

// ---------------- split-precision MFMA GEMM ----------------
// C = A@B (+bias)(+res) with A = Ah+Al, B^T rows = BTh+BTl (bf16 hi/lo pairs).
// acc += ah*bh + ah*bl + al*bh  (al*bl dropped, ~2^-18 rel)
// EPI 1: f32 out (bias+res). EPI 2: relu(bias) -> split bf16 out. EPI 3: plain f32 out.
template<int EPI>
__global__ __launch_bounds__(256) void mgemm_kernel(
    const bf16* __restrict__ Ah, const bf16* __restrict__ Al,
    const bf16* __restrict__ BTh, const bf16* __restrict__ BTl,
    const float* __restrict__ bias, const float* __restrict__ res,
    float* __restrict__ Cf, bf16* __restrict__ Cbh, bf16* __restrict__ Cbl,
    int K, int Ntot) {
  __shared__ __align__(16) bf16 Ash[64][72];
  __shared__ __align__(16) bf16 Asl[64][72];
  __shared__ __align__(16) bf16 Bsh[64][72];
  __shared__ __align__(16) bf16 Bsl[64][72];
  int tid = threadIdx.x;
  int m0 = blockIdx.x * 64, n0 = blockIdx.y * 64;
  int lane = tid & 63, wave = tid >> 6;
  int wr = wave >> 1, wc = wave & 1;
  int la = lane & 15, lb = lane >> 4;
  f32x4 acc[2][2] = {};
  for (int k0 = 0; k0 < K; k0 += 64) {
    #pragma unroll
    for (int p = 0; p < 2; ++p) {
      int ch = tid + p * 256;
      int r = ch >> 3, kc = (ch & 7) << 3;
      size_t ga = (size_t)(m0 + r) * K + k0 + kc;
      size_t gb = (size_t)(n0 + r) * K + k0 + kc;
      *reinterpret_cast<bfrag*>(&Ash[r][kc]) = *reinterpret_cast<const bfrag*>(&Ah[ga]);
      *reinterpret_cast<bfrag*>(&Asl[r][kc]) = *reinterpret_cast<const bfrag*>(&Al[ga]);
      *reinterpret_cast<bfrag*>(&Bsh[r][kc]) = *reinterpret_cast<const bfrag*>(&BTh[gb]);
      *reinterpret_cast<bfrag*>(&Bsl[r][kc]) = *reinterpret_cast<const bfrag*>(&BTl[gb]);
    }
    __syncthreads();
    #pragma unroll
    for (int ks = 0; ks < 64; ks += 32) {
      bfrag ah0 = *(const bfrag*)&Ash[wr * 32 + la][ks + lb * 8];
      bfrag ah1 = *(const bfrag*)&Ash[wr * 32 + 16 + la][ks + lb * 8];
      bfrag al0 = *(const bfrag*)&Asl[wr * 32 + la][ks + lb * 8];
      bfrag al1 = *(const bfrag*)&Asl[wr * 32 + 16 + la][ks + lb * 8];
      bfrag bh0 = *(const bfrag*)&Bsh[wc * 32 + la][ks + lb * 8];
      bfrag bh1 = *(const bfrag*)&Bsh[wc * 32 + 16 + la][ks + lb * 8];
      bfrag bl0 = *(const bfrag*)&Bsl[wc * 32 + la][ks + lb * 8];
      bfrag bl1 = *(const bfrag*)&Bsl[wc * 32 + 16 + la][ks + lb * 8];
      acc[0][0] = __builtin_amdgcn_mfma_f32_16x16x32_bf16(ah0, bh0, acc[0][0], 0, 0, 0);
      acc[0][0] = __builtin_amdgcn_mfma_f32_16x16x32_bf16(ah0, bl0, acc[0][0], 0, 0, 0);
      acc[0][0] = __builtin_amdgcn_mfma_f32_16x16x32_bf16(al0, bh0, acc[0][0], 0, 0, 0);
      acc[0][1] = __builtin_amdgcn_mfma_f32_16x16x32_bf16(ah0, bh1, acc[0][1], 0, 0, 0);
      acc[0][1] = __builtin_amdgcn_mfma_f32_16x16x32_bf16(ah0, bl1, acc[0][1], 0, 0, 0);
      acc[0][1] = __builtin_amdgcn_mfma_f32_16x16x32_bf16(al0, bh1, acc[0][1], 0, 0, 0);
      acc[1][0] = __builtin_amdgcn_mfma_f32_16x16x32_bf16(ah1, bh0, acc[1][0], 0, 0, 0);
      acc[1][0] = __builtin_amdgcn_mfma_f32_16x16x32_bf16(ah1, bl0, acc[1][0], 0, 0, 0);
      acc[1][0] = __builtin_amdgcn_mfma_f32_16x16x32_bf16(al1, bh0, acc[1][0], 0, 0, 0);
      acc[1][1] = __builtin_amdgcn_mfma_f32_16x16x32_bf16(ah1, bh1, acc[1][1], 0, 0, 0);
      acc[1][1] = __builtin_amdgcn_mfma_f32_16x16x32_bf16(ah1, bl1, acc[1][1], 0, 0, 0);
      acc[1][1] = __builtin_amdgcn_mfma_f32_16x16x32_bf16(al1, bh1, acc[1][1], 0, 0, 0);
    }
    __syncthreads();
  }
  // epilogue: C/D layout col=lane&15, row=(lane>>4)*4+j  [m89-verified]
  int r0 = lb * 4;
  #pragma unroll
  for (int ti = 0; ti < 2; ++ti)
    #pragma unroll
    for (int tj = 0; tj < 2; ++tj)
      #pragma unroll
      for (int j = 0; j < 4; ++j) {
        int m = m0 + wr * 32 + ti * 16 + r0 + j;
        int n = n0 + wc * 32 + tj * 16 + la;
        float v = acc[ti][tj][j];
        if (EPI == 1) {
          v += bias[n] + res[(size_t)m * Ntot + n];
          Cf[(size_t)m * Ntot + n] = v;
        } else if (EPI == 2) {
          v += bias[n];
          v = v > 0.f ? v : 0.f;
          bf16 vh, vl;
          split_bf16(v, vh, vl);
          Cbh[(size_t)m * Ntot + n] = vh;
          Cbl[(size_t)m * Ntot + n] = vl;
        } else {
          Cf[(size_t)m * Ntot + n] = v;
        }
      }
}

// ---------------- attention scores: register-tiled, 4 n-segments per (b,h) ----------------
__global__ __launch_bounds__(256) void score_kernel(const float* __restrict__ Q,
                                                    const float* __restrict__ Kmat,
                                                    float* __restrict__ SC) {
  int bh = blockIdx.x;
  int h = bh & 7, b = bh >> 3;
  int nbase = blockIdx.y * 51;
  int ncnt = min(51, S_ - nbase);
  __shared__ __align__(16) float qs[51][20];   // 80B rows: aligned float4
  __shared__ __align__(16) float ks[S_][20];
  int tid = threadIdx.x;
  for (int p = tid; p < 51 * 16; p += 256) {
    int r = p >> 4, d = p & 15;
    if (r < ncnt) qs[r][d] = Q[((size_t)(b * S_ + nbase + r)) * HD_ + h * D_ + d];
  }
  for (int p = tid; p < S_ * 16; p += 256) {
    int r = p >> 4, d = p & 15;
    ks[r][d] = Kmat[((size_t)(b * S_ + r)) * HD_ + h * D_ + d];
  }
  __syncthreads();
  float* out = SC + ((size_t)(b * H_ + h)) * S_ * S_;
  int tn = tid >> 4, tm = tid & 15;
  for (int n0 = tn * 2; n0 < ncnt; n0 += 32) {
    int n1v = (n0 + 1 < ncnt);
    f32x4 q0[4], q1[4];
    #pragma unroll
    for (int qd = 0; qd < 4; ++qd) {
      q0[qd] = *(const f32x4*)&qs[n0][qd * 4];
      q1[qd] = *(const f32x4*)&qs[n1v ? n0 + 1 : n0][qd * 4];
    }
    for (int m0 = tm * 2; m0 < S_; m0 += 32) {
      int m1v = (m0 + 1 < S_);
      float a00 = 0, a01 = 0, a10 = 0, a11 = 0;
      #pragma unroll
      for (int qd = 0; qd < 4; ++qd) {
        f32x4 k0 = *(const f32x4*)&ks[m0][qd * 4];
        f32x4 k1 = *(const f32x4*)&ks[m1v ? m0 + 1 : m0][qd * 4];
        #pragma unroll
        for (int c = 0; c < 4; ++c) {
          a00 += q0[qd][c] * k0[c];
          a01 += q0[qd][c] * k1[c];
          a10 += q1[qd][c] * k0[c];
          a11 += q1[qd][c] * k1[c];
        }
      }
      int gn = nbase + n0;
      out[(size_t)gn * S_ + m0] = a00;
      if (m1v) out[(size_t)gn * S_ + m0 + 1] = a01;
      if (n1v) {
        out[(size_t)(gn + 1) * S_ + m0] = a10;
        if (m1v) out[(size_t)(gn + 1) * S_ + m0 + 1] = a11;
      }
    }
  }
}

// ---------------- fused: edge-MLP + softmax + PV, NCH_ n's per block ----------------
__global__ __launch_bounds__(256) void attn_kernel(
    const float* __restrict__ SC, const float* __restrict__ RA,
    const float* __restrict__ A1w, const float* __restrict__ A1b,
    const float* __restrict__ A2w, const float* __restrict__ A2b,
    const float* __restrict__ V, bf16* __restrict__ OBh, bf16* __restrict__ OBl) {
  int blk = blockIdx.x;
  int b  = blk / NCHB_;
  int n0 = (blk % NCHB_) * NCH_;
  int NV = min(NCH_, S_ - n0);
  __shared__ float PL[NCH_][H_][PADM_];
  __shared__ float partial[2][NCH_][H_][D_];
  __shared__ float inv[NCH_][H_];
  int tid = threadIdx.x;

  // phase 1: edge MLP, weights via uniform scalar loads
  for (int e = tid; e < NV * S_; e += 256) {
    int nn = e / S_;
    int m  = e - nn * S_;
    const float* scp = SC + (((size_t)b * H_) * S_ + (n0 + nn)) * S_ + m;
    const float* rap = RA + (((size_t)b * H_) * S_ + (n0 + nn)) * S_ + m;
    float cc[TWOH_];
    #pragma unroll
    for (int h = 0; h < H_; ++h) {
      cc[h]      = scp[(size_t)h * S_ * S_];
      cc[H_ + h] = rap[(size_t)h * S_ * S_];
    }
    float h1[TWOH_];
    #pragma unroll
    for (int j = 0; j < TWOH_; ++j) h1[j] = A1b[j];
    #pragma unroll
    for (int i = 0; i < TWOH_; ++i) {
      float c = cc[i];
      #pragma unroll
      for (int j = 0; j < TWOH_; ++j)
        h1[j] += c * A1w[i * TWOH_ + j];
    }
    float agg[H_];
    #pragma unroll
    for (int h = 0; h < H_; ++h) agg[h] = A2b[h];
    #pragma unroll
    for (int j = 0; j < TWOH_; ++j) {
      float r = fmaxf(h1[j], 0.f);
      #pragma unroll
      for (int h = 0; h < H_; ++h)
        agg[h] += r * A2w[j * H_ + h];
    }
    #pragma unroll
    for (int h = 0; h < H_; ++h) PL[nn][h][m] = agg[h];
  }
  __syncthreads();

  // phase 2: softmax over m; 32 groups (nn,h) x 8 lanes
  {
    int g = tid >> 3, lane = tid & 7;
    int nn = g >> 3, h = g & 7;
    if (nn < NV) {
      float mx = -1e30f;
      for (int m = lane; m < S_; m += 8) mx = fmaxf(mx, PL[nn][h][m]);
      #pragma unroll
      for (int off = 4; off > 0; off >>= 1) mx = fmaxf(mx, __shfl_xor(mx, off, 8));
      float sum = 0.f;
      for (int m = lane; m < S_; m += 8) {
        float e = __expf(PL[nn][h][m] - mx);
        PL[nn][h][m] = e;
        sum += e;
      }
      #pragma unroll
      for (int off = 4; off > 0; off >>= 1) sum += __shfl_xor(sum, off, 8);
      if (lane == 0) inv[nn][h] = 1.f / sum;
    }
  }
  __syncthreads();

  // phase 3: PV
  {
    int half = tid >> 7, h = (tid >> 4) & 7, d = tid & 15;
    float a0 = 0.f, a1 = 0.f, a2 = 0.f, a3 = 0.f;
    const float* vp = V + (size_t)b * S_ * HD_ + h * D_ + d;
    for (int m = half; m < S_; m += 2) {
      float vv = vp[(size_t)m * HD_];
      a0 += PL[0][h][m] * vv;
      a1 += PL[1][h][m] * vv;
      a2 += PL[2][h][m] * vv;
      a3 += PL[3][h][m] * vv;
    }
    partial[half][0][h][d] = a0;
    partial[half][1][h][d] = a1;
    partial[half][2][h][d] = a2;
    partial[half][3][h][d] = a3;
  }
  __syncthreads();
  if (tid < 128) {
    int h = tid >> 4, d = tid & 15;
    #pragma unroll
    for (int nn = 0; nn < NCH_; ++nn)
      if (nn < NV) {
        float s = (partial[0][nn][h][d] + partial[1][nn][h][d]) * inv[nn][h];
        size_t o = ((size_t)b * S_ + (n0 + nn)) * HD_ + h * D_ + d;
        bf16 sh, sl;
        split_bf16(s, sh, sl);
        OBh[o] = sh;
        OBl[o] = sl;
      }
  }
}

// ---------------- instance norm (optional split-bf16 shadow output) ----------------
__global__ __launch_bounds__(512) void inorm_kernel(const float* __restrict__ Y,
                                                    const float* __restrict__ w,
                                                    const float* __restrict__ bb,
                                                    float* __restrict__ X,
                                                    bf16* __restrict__ XBh,
                                                    bf16* __restrict__ XBl) {
  int b = blockIdx.x;
  int tid = threadIdx.x;
  int e = tid & 127, sg = tid >> 7;
  __shared__ float ps[4][128], pss[4][128];
  const float* base = Y + (size_t)b * S_ * E_;
  float s = 0.f, ss = 0.f;
  for (int i = sg; i < S_; i += 4) {
    float v = base[(size_t)i * E_ + e];
    s += v; ss += v * v;
  }
  ps[sg][e] = s; pss[sg][e] = ss;
  __syncthreads();
  if (sg == 0) {
    s  = ps[0][e] + ps[1][e] + ps[2][e] + ps[3][e];
    ss = pss[0][e] + pss[1][e] + pss[2][e] + pss[3][e];
    float mean = s / S_;
    float var  = fmaxf(ss / S_ - mean * mean, 0.f);
    float scale = rsqrtf(var + 1e-5f) * w[e];
    ps[0][e]  = scale;
    pss[0][e] = bb[e] - mean * scale;
  }
  __syncthreads();
  float scale = ps[0][e], shift = pss[0][e];
  float* dst = X + (size_t)b * S_ * E_;
  for (int i = sg; i < S_; i += 4) {
    size_t idx = (size_t)i * E_ + e;
    float v = base[idx] * scale + shift;
    dst[idx] = v;
    if (XBh) {
      size_t gi = (size_t)b * S_ * E_ + idx;
      bf16 vh, vl;
      split_bf16(v, vh, vl);
      XBh[gi] = vh;
      XBl[gi] = vl;
    }
  }
}

extern "C" void kernel_launch(void* const* d_in, const int* in_sizes, int n_in,
                              void* d_out, int out_size, void* d_ws, size_t ws_size,
                              hipStream_t stream) {
  const float* depot = (const float*)d_in[0];
  const float* node  = (const float*)d_in[1];
  const float* RA    = (const float*)d_in[2];
  const float* Wd    = (const float*)d_in[3];
  const float* bd    = (const float*)d_in[4];
  const float* Wn    = (const float*)d_in[5];
  const float* bn    = (const float*)d_in[6];
  const float* Wq    = (const float*)d_in[7];
  const float* Wk    = (const float*)d_in[8];
  const float* Wv    = (const float*)d_in[9];
  const float* Wo    = (const float*)d_in[10];
  const float* bo    = (const float*)d_in[11];
  const float* A1w   = (const float*)d_in[12];
  const float* A1b   = (const float*)d_in[13];
  const float* A2w   = (const float*)d_in[14];
  const float* A2b   = (const float*)d_in[15];
  const float* n1w   = (const float*)d_in[16];
  const float* n1b   = (const float*)d_in[17];
  const float* n2w   = (const float*)d_in[18];
  const float* n2b   = (const float*)d_in[19];
  const float* F1w   = (const float*)d_in[20];
  const float* F1b   = (const float*)d_in[21];
  const float* F2w   = (const float*)d_in[22];
  const float* F2b   = (const float*)d_in[23];

  const size_t XSZ  = (size_t)B_ * S_ * E_;        // 1,646,592
  const size_t SCSZ = (size_t)B_ * H_ * S_ * S_;   // 20,685,312
  const size_t XBF  = XSZ / 2;                     // bf16 buffer in float-slots: 823,296
  float* ws = (float*)d_ws;
  float* X   = ws;                    // f32 [M][E]
  float* Q   = ws + XSZ;              // f32 [M][HD]; reused as OBh after score
  float* Kb  = ws + 2 * XSZ;          //              reused as OBl after score
  float* V   = ws + 3 * XSZ;
  float* SC  = ws + 4 * XSZ;          // SCSZ region, multi-purpose:
  float* TMP = SC;                                   // f32 [0, XSZ)
  bf16*  XBh = (bf16*)(SC + XSZ);                    // M*E bf16
  bf16*  XBl = (bf16*)(SC + XSZ + XBF);
  bf16*  HBh = (bf16*)(SC + XSZ + 2 * XBF);          // M*FF bf16
  bf16*  HBl = (bf16*)(SC + XSZ + 6 * XBF);
  float* tail = ws + 4 * XSZ + SCSZ;
  bf16*  WTh = (bf16*)tail;                          // 1,179,648 bf16 = 589,824 fl
  bf16*  WTl = (bf16*)(tail + 589824);
  // ws use: 4*XSZ + SCSZ + 1,179,648 floats = 28,451,328 fl = 113.8 MB
  bf16* OBh = (bf16*)Q;
  bf16* OBl = (bf16*)Kb;

  const int M = B_ * S_;  // 12864 = 201*64

  wcvt_kernel<<<4608, 256, 0, stream>>>(Wo, F1w, F2w, Wq, Wk, Wv, WTh, WTl);
  embed_kernel<<<(B_ * S_ * E_ + 255) / 256, 256, 0, stream>>>(depot, node, Wd, bd, Wn, bn, X, XBh, XBl);

  for (int l = 0; l < L_; ++l) {
    // QKV: split-precision MFMA from XB (embed for l=0, inorm2 otherwise)
    mgemm_kernel<3><<<dim3(M / 64, 2), 256, 0, stream>>>(
        XBh, XBl, WTh + 884736 + (size_t)l * 16384, WTl + 884736 + (size_t)l * 16384,
        nullptr, nullptr, Q, nullptr, nullptr, E_, HD_);
    mgemm_kernel<3><<<dim3(M / 64, 2), 256, 0, stream>>>(
        XBh, XBl, WTh + 983040 + (size_t)l * 16384, WTl + 983040 + (size_t)l * 16384,
        nullptr, nullptr, Kb, nullptr, nullptr, E_, HD_);
    mgemm_kernel<3><<<dim3(M / 64, 2), 256, 0, stream>>>(
        XBh, XBl, WTh + 1081344 + (size_t)l * 16384, WTl + 1081344 + (size_t)l * 16384,
        nullptr, nullptr, V, nullptr, nullptr, E_, HD_);
    score_kernel<<<dim3(B_ * H_, 4), 256, 0, stream>>>(Q, Kb, SC);
    attn_kernel<<<B_ * NCHB_, 256, 0, stream>>>(SC, RA,
        A1w + (size_t)l * TWOH_ * TWOH_, A1b + (size_t)l * TWOH_,
        A2w + (size_t)l * TWOH_ * H_,    A2b + (size_t)l * H_, V, OBh, OBl);
    // Wo: TMP = OB @ WoT^T + bo + X   (split precision)
    mgemm_kernel<1><<<dim3(M / 64, 2), 256, 0, stream>>>(
        OBh, OBl, WTh + (size_t)l * 16384, WTl + (size_t)l * 16384,
        bo + (size_t)l * E_, X, TMP, nullptr, nullptr, HD_, E_);
    inorm_kernel<<<B_, 512, 0, stream>>>(TMP, n1w + (size_t)l * E_, n1b + (size_t)l * E_, X, XBh, XBl);
    // F1: HB = relu(XB @ F1T^T + F1b)  (split bf16 out)
    mgemm_kernel<2><<<dim3(M / 64, 8), 256, 0, stream>>>(
        XBh, XBl, WTh + 98304 + (size_t)l * 65536, WTl + 98304 + (size_t)l * 65536,
        F1b + (size_t)l * FF_, nullptr, nullptr, HBh, HBl, E_, FF_);
    // F2: TMP = HB @ F2T^T + F2b + X
    mgemm_kernel<1><<<dim3(M / 64, 2), 256, 0, stream>>>(
        HBh, HBl, WTh + 491520 + (size_t)l * 65536, WTl + 491520 + (size_t)l * 65536,
        F2b + (size_t)l * E_, X, TMP, nullptr, nullptr, FF_, E_);
    float* dst = (l == L_ - 1) ? (float*)d_out : X;
    bf16* xh = (l == L_ - 1) ? nullptr : XBh;
    bf16* xl = (l == L_ - 1) ? nullptr : XBl;
    inorm_kernel<<<B_, 512, 0, stream>>>(TMP, n2w + (size_t)l * E_, n2b + (size_t)l * E_, dst, xh, xl);
  }
}

// Round 13
// 1507.333 us; speedup vs baseline: 3.4575x; 1.0612x over previous
//
#include <hip/hip_runtime.h>
#include <hip/hip_bf16.h>

// Problem constants
#define B_   64
#define N_   200
#define S_   201
#define E_   128
#define H_   8
#define D_   16
#define HD_  128
#define FF_  512
#define L_   6
#define TWOH_ 16
#define NCH_  4             // n's per attn block
#define NCHB_ 51            // ceil(S_/NCH_)
#define PADM_ 209           // padded m stride for PL (nn-stride 8*209 % 32 = 8 -> PV conflict-free)

typedef __hip_bfloat16 bf16;
typedef __attribute__((ext_vector_type(8))) short bfrag;   // 8 bf16 = 4 VGPRs
typedef __attribute__((ext_vector_type(4))) float f32x4;

__device__ __forceinline__ void split_bf16(float v, bf16& h, bf16& l) {
  h = __float2bfloat16(v);
  l = __float2bfloat16(v - __bfloat162float(h));
}

// ---------------- initial embedding (also emits split-bf16 shadow for QKV mgemm) ----------------
__global__ void embed_kernel(const float* __restrict__ depot, const float* __restrict__ node,
                             const float* __restrict__ Wd, const float* __restrict__ bd,
                             const float* __restrict__ Wn, const float* __restrict__ bn,
                             float* __restrict__ X, bf16* __restrict__ XBh, bf16* __restrict__ XBl) {
  int idx = blockIdx.x * blockDim.x + threadIdx.x;
  if (idx >= B_ * S_ * E_) return;
  int e  = idx & (E_ - 1);
  int bs = idx >> 7;
  int s  = bs % S_;
  int b  = bs / S_;
  float acc;
  if (s == 0) {
    acc = bd[e];
    #pragma unroll
    for (int i = 0; i < 3; ++i) acc += depot[b * 3 + i] * Wd[i * E_ + e];
  } else {
    acc = bn[e];
    const float* nd = node + ((size_t)b * N_ + (s - 1)) * 4;
    #pragma unroll
    for (int i = 0; i < 4; ++i) acc += nd[i] * Wn[i * E_ + e];
  }
  X[idx] = acc;
  bf16 hh, ll;
  split_bf16(acc, hh, ll);
  XBh[idx] = hh;
  XBl[idx] = ll;
}

// ---------------- weight transpose+convert to split bf16 (once per launch) ----------------
// layout (bf16 units): WoT 6x[128][128] @0 ; F1T 6x[512][128] @98304 ; F2T 6x[128][512] @491520
// QKT 6x[256][128] @884736 (Wq rows 0-127, Wk rows 128-255) ; WvT 6x[128][128] @1081344
__global__ void wcvt_kernel(const float* __restrict__ Wo, const float* __restrict__ F1w,
                            const float* __restrict__ F2w, const float* __restrict__ Wq,
                            const float* __restrict__ Wk, const float* __restrict__ Wv,
                            bf16* __restrict__ WTh, bf16* __restrict__ WTl) {
  int idx = blockIdx.x * blockDim.x + threadIdx.x;
  if (idx >= 1179648) return;
  float v;
  if (idx < 98304) {
    int l = idx / 16384, rr = idx % 16384;
    int e = rr / 128, h = rr % 128;
    v = Wo[(size_t)l * 16384 + h * 128 + e];
  } else if (idx < 491520) {
    int rem = idx - 98304;
    int l = rem / 65536, rr = rem % 65536;
    int f = rr / 128, e = rr % 128;
    v = F1w[(size_t)l * 65536 + e * 512 + f];
  } else if (idx < 884736) {
    int rem = idx - 491520;
    int l = rem / 65536, rr = rem % 65536;
    int e = rr / 512, f = rr % 512;
    v = F2w[(size_t)l * 65536 + f * 128 + e];
  } else if (idx < 1081344) {
    int rem = idx - 884736;
    int l = rem / 32768, rr = rem % 32768;   // [256][128] per layer
    int n = rr / 128, e = rr % 128;
    const float* src = (n < 128) ? Wq : Wk;
    int hd = n & 127;
    v = src[(size_t)l * 16384 + e * 128 + hd];
  } else {
    int rem = idx - 1081344;
    int l = rem / 16384, rr = rem % 16384;
    int hd = rr / 128, e = rr % 128;
    v = Wv[(size_t)l * 16384 + e * 128 + hd];
  }
  bf16 h, l2;
  split_bf16(v, h, l2);
  WTh[idx] = h;
  WTl[idx] = l2;
}

// ---------------- split-precision MFMA GEMM ----------------
// C = A@B (+bias)(+res) with A = Ah+Al, B^T rows = BTh+BTl (bf16 hi/lo pairs).
// acc += ah*bh + ah*bl + al*bh  (al*bl dropped, ~2^-18 rel)
// EPI 1: f32 out (bias+res). EPI 2: relu(bias) -> split bf16 out. EPI 3: plain f32 out.
template<int EPI>
__global__ __launch_bounds__(256) void mgemm_kernel(
    const bf16* __restrict__ Ah, const bf16* __restrict__ Al,
    const bf16* __restrict__ BTh, const bf16* __restrict__ BTl,
    const float* __restrict__ bias, const float* __restrict__ res,
    float* __restrict__ Cf, bf16* __restrict__ Cbh, bf16* __restrict__ Cbl,
    int K, int Ntot) {
  __shared__ __align__(16) bf16 Ash[64][72];
  __shared__ __align__(16) bf16 Asl[64][72];
  __shared__ __align__(16) bf16 Bsh[64][72];
  __shared__ __align__(16) bf16 Bsl[64][72];
  int tid = threadIdx.x;
  int m0 = blockIdx.x * 64, n0 = blockIdx.y * 64;
  int lane = tid & 63, wave = tid >> 6;
  int wr = wave >> 1, wc = wave & 1;
  int la = lane & 15, lb = lane >> 4;
  f32x4 acc[2][2] = {};
  for (int k0 = 0; k0 < K; k0 += 64) {
    #pragma unroll
    for (int p = 0; p < 2; ++p) {
      int ch = tid + p * 256;
      int r = ch >> 3, kc = (ch & 7) << 3;
      size_t ga = (size_t)(m0 + r) * K + k0 + kc;
      size_t gb = (size_t)(n0 + r) * K + k0 + kc;
      *reinterpret_cast<bfrag*>(&Ash[r][kc]) = *reinterpret_cast<const bfrag*>(&Ah[ga]);
      *reinterpret_cast<bfrag*>(&Asl[r][kc]) = *reinterpret_cast<const bfrag*>(&Al[ga]);
      *reinterpret_cast<bfrag*>(&Bsh[r][kc]) = *reinterpret_cast<const bfrag*>(&BTh[gb]);
      *reinterpret_cast<bfrag*>(&Bsl[r][kc]) = *reinterpret_cast<const bfrag*>(&BTl[gb]);
    }
    __syncthreads();
    #pragma unroll
    for (int ks = 0; ks < 64; ks += 32) {
      bfrag ah0 = *(const bfrag*)&Ash[wr * 32 + la][ks + lb * 8];
      bfrag ah1 = *(const bfrag*)&Ash[wr * 32 + 16 + la][ks + lb * 8];
      bfrag al0 = *(const bfrag*)&Asl[wr * 32 + la][ks + lb * 8];
      bfrag al1 = *(const bfrag*)&Asl[wr * 32 + 16 + la][ks + lb * 8];
      bfrag bh0 = *(const bfrag*)&Bsh[wc * 32 + la][ks + lb * 8];
      bfrag bh1 = *(const bfrag*)&Bsh[wc * 32 + 16 + la][ks + lb * 8];
      bfrag bl0 = *(const bfrag*)&Bsl[wc * 32 + la][ks + lb * 8];
      bfrag bl1 = *(const bfrag*)&Bsl[wc * 32 + 16 + la][ks + lb * 8];
      acc[0][0] = __builtin_amdgcn_mfma_f32_16x16x32_bf16(ah0, bh0, acc[0][0], 0, 0, 0);
      acc[0][0] = __builtin_amdgcn_mfma_f32_16x16x32_bf16(ah0, bl0, acc[0][0], 0, 0, 0);
      acc[0][0] = __builtin_amdgcn_mfma_f32_16x16x32_bf16(al0, bh0, acc[0][0], 0, 0, 0);
      acc[0][1] = __builtin_amdgcn_mfma_f32_16x16x32_bf16(ah0, bh1, acc[0][1], 0, 0, 0);
      acc[0][1] = __builtin_amdgcn_mfma_f32_16x16x32_bf16(ah0, bl1, acc[0][1], 0, 0, 0);
      acc[0][1] = __builtin_amdgcn_mfma_f32_16x16x32_bf16(al0, bh1, acc[0][1], 0, 0, 0);
      acc[1][0] = __builtin_amdgcn_mfma_f32_16x16x32_bf16(ah1, bh0, acc[1][0], 0, 0, 0);
      acc[1][0] = __builtin_amdgcn_mfma_f32_16x16x32_bf16(ah1, bl0, acc[1][0], 0, 0, 0);
      acc[1][0] = __builtin_amdgcn_mfma_f32_16x16x32_bf16(al1, bh0, acc[1][0], 0, 0, 0);
      acc[1][1] = __builtin_amdgcn_mfma_f32_16x16x32_bf16(ah1, bh1, acc[1][1], 0, 0, 0);
      acc[1][1] = __builtin_amdgcn_mfma_f32_16x16x32_bf16(ah1, bl1, acc[1][1], 0, 0, 0);
      acc[1][1] = __builtin_amdgcn_mfma_f32_16x16x32_bf16(al1, bh1, acc[1][1], 0, 0, 0);
    }
    __syncthreads();
  }
  // epilogue: C/D layout col=lane&15, row=(lane>>4)*4+j  [m89-verified]
  int r0 = lb * 4;
  #pragma unroll
  for (int ti = 0; ti < 2; ++ti)
    #pragma unroll
    for (int tj = 0; tj < 2; ++tj)
      #pragma unroll
      for (int j = 0; j < 4; ++j) {
        int m = m0 + wr * 32 + ti * 16 + r0 + j;
        int n = n0 + wc * 32 + tj * 16 + la;
        float v = acc[ti][tj][j];
        if (EPI == 1) {
          v += bias[n] + res[(size_t)m * Ntot + n];
          Cf[(size_t)m * Ntot + n] = v;
        } else if (EPI == 2) {
          v += bias[n];
          v = v > 0.f ? v : 0.f;
          bf16 vh, vl;
          split_bf16(v, vh, vl);
          Cbh[(size_t)m * Ntot + n] = vh;
          Cbl[(size_t)m * Ntot + n] = vl;
        } else {
          Cf[(size_t)m * Ntot + n] = v;
        }
      }
}

// ---------------- attention scores: register-tiled; QK packed rows of 256 ----------------
__global__ __launch_bounds__(256) void score_kernel(const float* __restrict__ QK,
                                                    float* __restrict__ SC) {
  int bh = blockIdx.x;
  int h = bh & 7, b = bh >> 3;
  int nbase = blockIdx.y * 51;
  int ncnt = min(51, S_ - nbase);
  __shared__ __align__(16) float qs[51][20];   // 80B rows: aligned float4
  __shared__ __align__(16) float ks[S_][20];
  int tid = threadIdx.x;
  for (int p = tid; p < 51 * 16; p += 256) {
    int r = p >> 4, d = p & 15;
    if (r < ncnt) qs[r][d] = QK[((size_t)(b * S_ + nbase + r)) * 256 + h * D_ + d];
  }
  for (int p = tid; p < S_ * 16; p += 256) {
    int r = p >> 4, d = p & 15;
    ks[r][d] = QK[((size_t)(b * S_ + r)) * 256 + 128 + h * D_ + d];
  }
  __syncthreads();
  float* out = SC + ((size_t)(b * H_ + h)) * S_ * S_;
  int tn = tid >> 4, tm = tid & 15;
  for (int n0 = tn * 2; n0 < ncnt; n0 += 32) {
    int n1v = (n0 + 1 < ncnt);
    f32x4 q0[4], q1[4];
    #pragma unroll
    for (int qd = 0; qd < 4; ++qd) {
      q0[qd] = *(const f32x4*)&qs[n0][qd * 4];
      q1[qd] = *(const f32x4*)&qs[n1v ? n0 + 1 : n0][qd * 4];
    }
    for (int m0 = tm * 2; m0 < S_; m0 += 32) {
      int m1v = (m0 + 1 < S_);
      float a00 = 0, a01 = 0, a10 = 0, a11 = 0;
      #pragma unroll
      for (int qd = 0; qd < 4; ++qd) {
        f32x4 k0 = *(const f32x4*)&ks[m0][qd * 4];
        f32x4 k1 = *(const f32x4*)&ks[m1v ? m0 + 1 : m0][qd * 4];
        #pragma unroll
        for (int c = 0; c < 4; ++c) {
          a00 += q0[qd][c] * k0[c];
          a01 += q0[qd][c] * k1[c];
          a10 += q1[qd][c] * k0[c];
          a11 += q1[qd][c] * k1[c];
        }
      }
      int gn = nbase + n0;
      out[(size_t)gn * S_ + m0] = a00;
      if (m1v) out[(size_t)gn * S_ + m0 + 1] = a01;
      if (n1v) {
        out[(size_t)(gn + 1) * S_ + m0] = a10;
        if (m1v) out[(size_t)(gn + 1) * S_ + m0 + 1] = a11;
      }
    }
  }
}

// ---------------- fused: edge-MLP + softmax + PV, NCH_ n's per block ----------------
// Phase 1: 4 compile-time slots per thread, ALL loads issued before compute.
__global__ __launch_bounds__(256) void attn_kernel(
    const float* __restrict__ SC, const float* __restrict__ RA,
    const float* __restrict__ A1w, const float* __restrict__ A1b,
    const float* __restrict__ A2w, const float* __restrict__ A2b,
    const float* __restrict__ V, bf16* __restrict__ OBh, bf16* __restrict__ OBl) {
  int blk = blockIdx.x;
  int b  = blk / NCHB_;
  int n0 = (blk % NCHB_) * NCH_;
  int NV = min(NCH_, S_ - n0);
  __shared__ float PL[NCH_][H_][PADM_];
  __shared__ float partial[2][NCH_][H_][D_];
  __shared__ float inv[NCH_][H_];
  int tid = threadIdx.x;

  // ---- phase 1: batched loads for 4 slots, then compute ----
  {
    float cc[4][TWOH_];
    int   mm[4], nnv[4];
    bool  val[4];
    #pragma unroll
    for (int s = 0; s < 4; ++s) {
      int e = tid + s * 256;
      val[s] = (e < NV * S_);
      int nn = e / S_;
      int m  = e - nn * S_;
      if (!val[s]) { nn = 0; m = 0; }   // clamp: address stays in-bounds
      nnv[s] = nn; mm[s] = m;
      const float* scp = SC + (((size_t)b * H_) * S_ + (n0 + nn)) * S_ + m;
      const float* rap = RA + (((size_t)b * H_) * S_ + (n0 + nn)) * S_ + m;
      #pragma unroll
      for (int h = 0; h < H_; ++h) {
        cc[s][h]      = scp[(size_t)h * S_ * S_];
        cc[s][H_ + h] = rap[(size_t)h * S_ * S_];
      }
    }
    #pragma unroll
    for (int s = 0; s < 4; ++s) {
      if (!val[s]) continue;
      float h1[TWOH_];
      #pragma unroll
      for (int j = 0; j < TWOH_; ++j) h1[j] = A1b[j];        // uniform -> s_load
      #pragma unroll
      for (int i = 0; i < TWOH_; ++i) {
        float c = cc[s][i];
        #pragma unroll
        for (int j = 0; j < TWOH_; ++j)
          h1[j] += c * A1w[i * TWOH_ + j];                   // uniform -> SGPR operand
      }
      float agg[H_];
      #pragma unroll
      for (int h = 0; h < H_; ++h) agg[h] = A2b[h];
      #pragma unroll
      for (int j = 0; j < TWOH_; ++j) {
        float r = fmaxf(h1[j], 0.f);
        #pragma unroll
        for (int h = 0; h < H_; ++h)
          agg[h] += r * A2w[j * H_ + h];
      }
      #pragma unroll
      for (int h = 0; h < H_; ++h) PL[nnv[s]][h][mm[s]] = agg[h];
    }
  }
  __syncthreads();

  // ---- phase 2: softmax over m; 32 groups (nn,h) x 8 lanes ----
  {
    int g = tid >> 3, lane = tid & 7;
    int nn = g >> 3, h = g & 7;
    if (nn < NV) {
      float mx = -1e30f;
      for (int m = lane; m < S_; m += 8) mx = fmaxf(mx, PL[nn][h][m]);
      #pragma unroll
      for (int off = 4; off > 0; off >>= 1) mx = fmaxf(mx, __shfl_xor(mx, off, 8));
      float sum = 0.f;
      for (int m = lane; m < S_; m += 8) {
        float e = __expf(PL[nn][h][m] - mx);
        PL[nn][h][m] = e;
        sum += e;
      }
      #pragma unroll
      for (int off = 4; off > 0; off >>= 1) sum += __shfl_xor(sum, off, 8);
      if (lane == 0) inv[nn][h] = 1.f / sum;
    }
  }
  __syncthreads();

  // ---- phase 3: PV, all 256 threads: (m-parity) x (h,d), 4 n-accumulators per V load ----
  {
    int half = tid >> 7, h = (tid >> 4) & 7, d = tid & 15;
    float a0 = 0.f, a1 = 0.f, a2 = 0.f, a3 = 0.f;
    const float* vp = V + (size_t)b * S_ * HD_ + h * D_ + d;
    for (int m = half; m < S_; m += 2) {
      float vv = vp[(size_t)m * HD_];
      a0 += PL[0][h][m] * vv;
      a1 += PL[1][h][m] * vv;
      a2 += PL[2][h][m] * vv;
      a3 += PL[3][h][m] * vv;
    }
    partial[half][0][h][d] = a0;
    partial[half][1][h][d] = a1;
    partial[half][2][h][d] = a2;
    partial[half][3][h][d] = a3;
  }
  __syncthreads();
  if (tid < 128) {
    int h = tid >> 4, d = tid & 15;
    #pragma unroll
    for (int nn = 0; nn < NCH_; ++nn)
      if (nn < NV) {
        float s = (partial[0][nn][h][d] + partial[1][nn][h][d]) * inv[nn][h];
        size_t o = ((size_t)b * S_ + (n0 + nn)) * HD_ + h * D_ + d;
        bf16 sh, sl;
        split_bf16(s, sh, sl);
        OBh[o] = sh;
        OBl[o] = sl;
      }
  }
}

// ---------------- instance norm (optional split-bf16 shadow output) ----------------
__global__ __launch_bounds__(512) void inorm_kernel(const float* __restrict__ Y,
                                                    const float* __restrict__ w,
                                                    const float* __restrict__ bb,
                                                    float* __restrict__ X,
                                                    bf16* __restrict__ XBh,
                                                    bf16* __restrict__ XBl) {
  int b = blockIdx.x;
  int tid = threadIdx.x;
  int e = tid & 127, sg = tid >> 7;
  __shared__ float ps[4][128], pss[4][128];
  const float* base = Y + (size_t)b * S_ * E_;
  float s = 0.f, ss = 0.f;
  for (int i = sg; i < S_; i += 4) {
    float v = base[(size_t)i * E_ + e];
    s += v; ss += v * v;
  }
  ps[sg][e] = s; pss[sg][e] = ss;
  __syncthreads();
  if (sg == 0) {
    s  = ps[0][e] + ps[1][e] + ps[2][e] + ps[3][e];
    ss = pss[0][e] + pss[1][e] + pss[2][e] + pss[3][e];
    float mean = s / S_;
    float var  = fmaxf(ss / S_ - mean * mean, 0.f);
    float scale = rsqrtf(var + 1e-5f) * w[e];
    ps[0][e]  = scale;
    pss[0][e] = bb[e] - mean * scale;
  }
  __syncthreads();
  float scale = ps[0][e], shift = pss[0][e];
  float* dst = X + (size_t)b * S_ * E_;
  for (int i = sg; i < S_; i += 4) {
    size_t idx = (size_t)i * E_ + e;
    float v = base[idx] * scale + shift;
    dst[idx] = v;
    if (XBh) {
      size_t gi = (size_t)b * S_ * E_ + idx;
      bf16 vh, vl;
      split_bf16(v, vh, vl);
      XBh[gi] = vh;
      XBl[gi] = vl;
    }
  }
}

extern "C" void kernel_launch(void* const* d_in, const int* in_sizes, int n_in,
                              void* d_out, int out_size, void* d_ws, size_t ws_size,
                              hipStream_t stream) {
  const float* depot = (const float*)d_in[0];
  const float* node  = (const float*)d_in[1];
  const float* RA    = (const float*)d_in[2];
  const float* Wd    = (const float*)d_in[3];
  const float* bd    = (const float*)d_in[4];
  const float* Wn    = (const float*)d_in[5];
  const float* bn    = (const float*)d_in[6];
  const float* Wq    = (const float*)d_in[7];
  const float* Wk    = (const float*)d_in[8];
  const float* Wv    = (const float*)d_in[9];
  const float* Wo    = (const float*)d_in[10];
  const float* bo    = (const float*)d_in[11];
  const float* A1w   = (const float*)d_in[12];
  const float* A1b   = (const float*)d_in[13];
  const float* A2w   = (const float*)d_in[14];
  const float* A2b   = (const float*)d_in[15];
  const float* n1w   = (const float*)d_in[16];
  const float* n1b   = (const float*)d_in[17];
  const float* n2w   = (const float*)d_in[18];
  const float* n2b   = (const float*)d_in[19];
  const float* F1w   = (const float*)d_in[20];
  const float* F1b   = (const float*)d_in[21];
  const float* F2w   = (const float*)d_in[22];
  const float* F2b   = (const float*)d_in[23];

  const size_t XSZ  = (size_t)B_ * S_ * E_;        // 1,646,592
  const size_t SCSZ = (size_t)B_ * H_ * S_ * S_;   // 20,685,312
  const size_t XBF  = XSZ / 2;                     // bf16 buffer in float-slots: 823,296
  float* ws = (float*)d_ws;
  float* X   = ws;                    // f32 [M][E]
  float* QK  = ws + XSZ;              // f32 [M][256] packed Q|K; reused as OBh/OBl after score
  float* V   = ws + 3 * XSZ;
  float* SC  = ws + 4 * XSZ;          // SCSZ region, multi-purpose:
  float* TMP = SC;                                   // f32 [0, XSZ)
  bf16*  XBh = (bf16*)(SC + XSZ);                    // M*E bf16
  bf16*  XBl = (bf16*)(SC + XSZ + XBF);
  bf16*  HBh = (bf16*)(SC + XSZ + 2 * XBF);          // M*FF bf16
  bf16*  HBl = (bf16*)(SC + XSZ + 6 * XBF);
  float* tail = ws + 4 * XSZ + SCSZ;
  bf16*  WTh = (bf16*)tail;                          // 1,179,648 bf16 = 589,824 fl
  bf16*  WTl = (bf16*)(tail + 589824);
  // ws use: 4*XSZ + SCSZ + 1,179,648 floats = 28,451,328 fl = 113.8 MB
  bf16* OBh = (bf16*)QK;              // aliases QK region (dead after score)
  bf16* OBl = (bf16*)(ws + 2 * XSZ);

  const int M = B_ * S_;  // 12864 = 201*64

  wcvt_kernel<<<4608, 256, 0, stream>>>(Wo, F1w, F2w, Wq, Wk, Wv, WTh, WTl);
  embed_kernel<<<(B_ * S_ * E_ + 255) / 256, 256, 0, stream>>>(depot, node, Wd, bd, Wn, bn, X, XBh, XBl);

  for (int l = 0; l < L_; ++l) {
    // QK fused: [M][256] = XB @ [Wq|Wk]  (split precision)
    mgemm_kernel<3><<<dim3(M / 64, 4), 256, 0, stream>>>(
        XBh, XBl, WTh + 884736 + (size_t)l * 32768, WTl + 884736 + (size_t)l * 32768,
        nullptr, nullptr, QK, nullptr, nullptr, E_, 256);
    // V: [M][128]
    mgemm_kernel<3><<<dim3(M / 64, 2), 256, 0, stream>>>(
        XBh, XBl, WTh + 1081344 + (size_t)l * 16384, WTl + 1081344 + (size_t)l * 16384,
        nullptr, nullptr, V, nullptr, nullptr, E_, HD_);
    score_kernel<<<dim3(B_ * H_, 4), 256, 0, stream>>>(QK, SC);
    attn_kernel<<<B_ * NCHB_, 256, 0, stream>>>(SC, RA,
        A1w + (size_t)l * TWOH_ * TWOH_, A1b + (size_t)l * TWOH_,
        A2w + (size_t)l * TWOH_ * H_,    A2b + (size_t)l * H_, V, OBh, OBl);
    // Wo: TMP = OB @ WoT^T + bo + X   (split precision)
    mgemm_kernel<1><<<dim3(M / 64, 2), 256, 0, stream>>>(
        OBh, OBl, WTh + (size_t)l * 16384, WTl + (size_t)l * 16384,
        bo + (size_t)l * E_, X, TMP, nullptr, nullptr, HD_, E_);
    inorm_kernel<<<B_, 512, 0, stream>>>(TMP, n1w + (size_t)l * E_, n1b + (size_t)l * E_, X, XBh, XBl);
    // F1: HB = relu(XB @ F1T^T + F1b)  (split bf16 out)
    mgemm_kernel<2><<<dim3(M / 64, 8), 256, 0, stream>>>(
        XBh, XBl, WTh + 98304 + (size_t)l * 65536, WTl + 98304 + (size_t)l * 65536,
        F1b + (size_t)l * FF_, nullptr, nullptr, HBh, HBl, E_, FF_);
    // F2: TMP = HB @ F2T^T + F2b + X
    mgemm_kernel<1><<<dim3(M / 64, 2), 256, 0, stream>>>(
        HBh, HBl, WTh + 491520 + (size_t)l * 65536, WTl + 491520 + (size_t)l * 65536,
        F2b + (size_t)l * E_, X, TMP, nullptr, nullptr, FF_, E_);
    float* dst = (l == L_ - 1) ? (float*)d_out : X;
    bf16* xh = (l == L_ - 1) ? nullptr : XBh;
    bf16* xl = (l == L_ - 1) ? nullptr : XBl;
    inorm_kernel<<<B_, 512, 0, stream>>>(TMP, n2w + (size_t)l * E_, n2b + (size_t)l * E_, dst, xh, xl);
  }
}